// Round 8
// baseline (178.775 us; speedup 1.0000x reference)
//
#include <hip/hip_runtime.h>
#include <hip/hip_fp16.h>

typedef _Float16 f16x8 __attribute__((ext_vector_type(8)));
typedef float f32x4 __attribute__((ext_vector_type(4)));

#define NPB 256      // nodes per bucket (dst >> 8)
#define FCHUNK 6144  // edges per fill block (24 per thread)
#define MAXBK 512    // LDS bucket array size (>= NBUCK=391)

// x fp32 -> fp16
__global__ void k_xhalf(const float4* __restrict__ x4, __half2* __restrict__ xh2, int n4) {
  int i = blockIdx.x * blockDim.x + threadIdx.x;
  if (i < n4) {
    float4 v = x4[i];
    __half2 a, b;
    a.x = __float2half_rn(v.x); a.y = __float2half_rn(v.y);
    b.x = __float2half_rn(v.z); b.y = __float2half_rn(v.w);
    xh2[2 * i] = a;
    xh2[2 * i + 1] = b;
  }
}

// global per-bucket histogram (block-local LDS first, one flush per bucket)
__global__ void k_hist(const int* __restrict__ dst, int* __restrict__ bins,
                       int E, int chunk) {
  __shared__ int lh[MAXBK];
  for (int i = threadIdx.x; i < MAXBK; i += blockDim.x) lh[i] = 0;
  __syncthreads();
  int e0 = blockIdx.x * chunk;
  int e1 = min(e0 + chunk, E);
  for (int e = e0 + threadIdx.x; e < e1; e += blockDim.x)
    atomicAdd(&lh[dst[e] >> 8], 1);
  __syncthreads();
  for (int i = threadIdx.x; i < MAXBK; i += blockDim.x)
    if (lh[i]) atomicAdd(&bins[i], lh[i]);
}

// exclusive scan of nb bins (nb <= 4096), writes binoff (+sentinel) and cursors
__global__ void k_scan1(const int* __restrict__ bins, int* __restrict__ binoff,
                        int* __restrict__ cur, int nb, int E) {
  __shared__ int lds[1024];
  int t = threadIdx.x;
  int g0 = t * 4;
  int v[4]; int s = 0;
  for (int i = 0; i < 4; ++i) { int idx = g0 + i; v[i] = (idx < nb) ? bins[idx] : 0; s += v[i]; }
  lds[t] = s;
  __syncthreads();
  for (int d = 1; d < 1024; d <<= 1) {
    int a = (t >= d) ? lds[t - d] : 0;
    __syncthreads();
    lds[t] += a;
    __syncthreads();
  }
  int ex = lds[t] - s;
  for (int i = 0; i < 4; ++i) {
    int idx = g0 + i;
    if (idx < nb) { binoff[idx] = ex; cur[idx] = ex; }
    ex += v[i];
  }
  if (t == 0) binoff[nb] = E;
}

// scatter edges into bucket segments with per-(block,bucket) reservation:
// LDS hist -> one global atomic per bucket -> direct scatter via LDS cursors.
__global__ __launch_bounds__(256) void k_fill3(const int* __restrict__ src,
    const int* __restrict__ dst, int* __restrict__ cur,
    int* __restrict__ packed, int E) {
  __shared__ int lh[MAXBK];
  __shared__ int gbase[MAXBK];
  int t = threadIdx.x;
  int e0 = blockIdx.x * FCHUNK;
  int e1 = min(e0 + FCHUNK, E);
  for (int i = t; i < MAXBK; i += 256) lh[i] = 0;
  __syncthreads();
  int dv[24];
#pragma unroll
  for (int i = 0; i < 24; ++i) {
    int e = e0 + t + i * 256;
    dv[i] = (e < e1) ? dst[e] : -1;
    if (dv[i] >= 0) atomicAdd(&lh[dv[i] >> 8], 1);
  }
  __syncthreads();
  for (int i = t; i < MAXBK; i += 256) {
    int c = lh[i];
    gbase[i] = c ? atomicAdd(&cur[i], c) : 0;
    lh[i] = 0;  // reuse as local cursor
  }
  __syncthreads();
#pragma unroll
  for (int i = 0; i < 24; ++i) {
    int d = dv[i];
    if (d >= 0) {
      int e = e0 + t + i * 256;
      int bk = d >> 8;
      int lp = atomicAdd(&lh[bk], 1);
      packed[gbase[bk] + lp] = src[e] | ((d & 255) << 20);
    }
  }
}

// per-bucket counting sort: bucket segment -> per-node CSR (+ offA, deg)
__global__ __launch_bounds__(256) void k_sort(const int* __restrict__ packed,
    const int* __restrict__ binoff, int* __restrict__ csr,
    int* __restrict__ offA, int* __restrict__ deg, int N) {
  __shared__ int hist[NPB];
  __shared__ int sc[NPB];
  __shared__ int curs[NPB];
  int b = blockIdx.x, t = threadIdx.x;
  hist[t] = 0;
  __syncthreads();
  int e0 = binoff[b], e1 = binoff[b + 1];
  for (int e = e0 + t; e < e1; e += 256)
    atomicAdd(&hist[(packed[e] >> 20) & 255], 1);
  __syncthreads();
  int v = hist[t];
  sc[t] = v;
  __syncthreads();
  for (int d = 1; d < 256; d <<= 1) {
    int a = (t >= d) ? sc[t - d] : 0;
    __syncthreads();
    sc[t] += a;
    __syncthreads();
  }
  int ex = e0 + sc[t] - v;   // global CSR start for this node
  curs[t] = ex;
  int n = b * NPB + t;
  if (n < N) { offA[n] = ex; deg[n] = v; }
  __syncthreads();
  for (int e = e0 + t; e < e1; e += 256) {
    int pk = packed[e];
    int p = atomicAdd(&curs[(pk >> 20) & 255], 1);
    csr[p] = pk & 0xFFFFF;
  }
}

// S[n] = sum over incoming edges of x[src].
// half2 layout: lane&31 = feature pair, lane>>5 = edge slot (2 edges/step,
// 16 edges in flight), fp32 accumulate, shfl_xor(32) merge, fp16 out.
__global__ void k_agg(const __half2* __restrict__ xh2, const int* __restrict__ offA,
                      const int* __restrict__ deg, const int* __restrict__ csr,
                      __half2* __restrict__ Sh2, int N) {
  int t = threadIdx.x;
  int lane = t & 63;
  int slot = lane >> 5;       // 0/1: which edge of the pair
  int f = lane & 31;          // feature-pair index
  int wid = (blockIdx.x * blockDim.x + t) >> 6;
  int nw = (gridDim.x * blockDim.x) >> 6;
  for (int n = wid; n < N; n += nw) {
    int j0 = offA[n], dg = deg[n];
    float a0 = 0.f, a1 = 0.f;
    int j = 0;
    for (; j + 16 <= dg; j += 16) {
#pragma unroll
      for (int i = 0; i < 8; ++i) {
        int s = csr[j0 + j + 2 * i + slot];
        float2 vf = __half22float2(xh2[(size_t)s * 32 + f]);
        a0 += vf.x; a1 += vf.y;
      }
    }
    for (; j + 2 <= dg; j += 2) {
      int s = csr[j0 + j + slot];
      float2 vf = __half22float2(xh2[(size_t)s * 32 + f]);
      a0 += vf.x; a1 += vf.y;
    }
    if (j < dg && slot == 0) {  // odd tail
      int s = csr[j0 + j];
      float2 vf = __half22float2(xh2[(size_t)s * 32 + f]);
      a0 += vf.x; a1 += vf.y;
    }
    a0 += __shfl_xor(a0, 32);
    a1 += __shfl_xor(a1, 32);
    if (slot == 0) {
      __half2 o;
      o.x = __float2half_rn(a0);
      o.y = __float2half_rn(a1);
      Sh2[(size_t)n * 32 + f] = o;
    }
  }
}

// build fp16 B-fragments for the 3 64x64 matrices + c2
// frag f = mat*8 + kk*4 + ct; entry t = lane*8+j holds M[kk*32+(lane>>4)*8+j][ct*16+(lane&15)]
__global__ void k_mats2(const float* __restrict__ We, const float* __restrict__ be,
                        const float* __restrict__ Wn, __half* __restrict__ Wfrag,
                        float* __restrict__ c2) {
  int b = blockIdx.x, t = threadIdx.x;
  if (b < 24) {
    int mat = b >> 3, kk = (b >> 2) & 1, ct = b & 3;
    int lane = t >> 3, j = t & 7;
    int k = kk * 32 + ((lane >> 4) & 3) * 8 + j;
    int col = ct * 16 + (lane & 15);
    float v;
    if (mat == 0) {
      v = Wn[k * 64 + col];
    } else if (mat == 1) {
      float a = 0.f;
      for (int m = 0; m < 64; ++m) a += We[k * 64 + m] * Wn[(64 + m) * 64 + col];
      v = a;
    } else {
      float a = 0.f;
      for (int m = 0; m < 64; ++m) a += We[(64 + k) * 64 + m] * Wn[(64 + m) * 64 + col];
      v = a;
    }
    Wfrag[b * 512 + t] = __float2half_rn(v);
  } else if (t < 64) {
    float a = 0.f;
    for (int m = 0; m < 64; ++m) a += be[m] * Wn[(64 + m) * 64 + t];
    c2[t] = a;
  }
}

// node model via MFMA: h = PReLU(x@M1 + S@M2 + deg*(x@M3 + c2) + b); h -> fp16
__global__ __launch_bounds__(256) void k_nodeM(const __half* __restrict__ xh,
    const __half* __restrict__ Sh, const int* __restrict__ deg,
    const __half* __restrict__ Wfrag, const float* __restrict__ c2,
    const float* __restrict__ bnode, const float* __restrict__ pa,
    __half* __restrict__ Hh, int N) {
  const f16x8* WF = (const f16x8*)Wfrag;
  int t = threadIdx.x, lane = t & 63;
  f16x8 B[24];
#pragma unroll
  for (int f = 0; f < 24; ++f) B[f] = WF[f * 64 + lane];
  float slope = pa[0];
  int wid = (blockIdx.x * blockDim.x + t) >> 6;
  int nw = (gridDim.x * blockDim.x) >> 6;
  int ntile = N >> 4;
  int r = lane & 15, g = lane >> 4;
  for (int tile = wid; tile < ntile; tile += nw) {
    int n0 = tile << 4;
    float dg[4];
#pragma unroll
    for (int q = 0; q < 4; ++q) dg[q] = (float)deg[n0 + g * 4 + q];
    const f16x8* xp = (const f16x8*)(xh + (size_t)(n0 + r) * 64 + g * 8);
    const f16x8* sp = (const f16x8*)(Sh + (size_t)(n0 + r) * 64 + g * 8);
    f16x8 ax0 = xp[0], ax1 = xp[4];
    f16x8 as0 = sp[0], as1 = sp[4];
    f32x4 accA[4], accB[4];
#pragma unroll
    for (int ct = 0; ct < 4; ++ct) {
      f32x4 a = {0.f, 0.f, 0.f, 0.f};
      a = __builtin_amdgcn_mfma_f32_16x16x32_f16(ax0, B[0 + ct], a, 0, 0, 0);
      a = __builtin_amdgcn_mfma_f32_16x16x32_f16(ax1, B[4 + ct], a, 0, 0, 0);
      a = __builtin_amdgcn_mfma_f32_16x16x32_f16(as0, B[8 + ct], a, 0, 0, 0);
      a = __builtin_amdgcn_mfma_f32_16x16x32_f16(as1, B[12 + ct], a, 0, 0, 0);
      accA[ct] = a;
      f32x4 bb = {0.f, 0.f, 0.f, 0.f};
      bb = __builtin_amdgcn_mfma_f32_16x16x32_f16(ax0, B[16 + ct], bb, 0, 0, 0);
      bb = __builtin_amdgcn_mfma_f32_16x16x32_f16(ax1, B[20 + ct], bb, 0, 0, 0);
      accB[ct] = bb;
    }
#pragma unroll
    for (int ct = 0; ct < 4; ++ct) {
      int c = ct * 16 + r;
      float cc = c2[c], bv = bnode[c];
#pragma unroll
      for (int q = 0; q < 4; ++q) {
        float hv = accA[ct][q] + dg[q] * (accB[ct][q] + cc) + bv;
        hv = hv >= 0.f ? hv : slope * hv;
        Hh[(size_t)(n0 + g * 4 + q) * 64 + c] = __float2half_rn(hv);
      }
    }
  }
}

// column sums/sumsq over Hh: reg accumulate -> LDS atomics -> 128 global atomics/block
__global__ __launch_bounds__(256) void k_stats(const __half2* __restrict__ hh,
    float* __restrict__ stats, int n2) {
  __shared__ float ls[128];
  int t = threadIdx.x;
  if (t < 128) ls[t] = 0.f;
  __syncthreads();
  int cb = (t & 31) * 2;
  float s0 = 0.f, q0 = 0.f, s1 = 0.f, q1 = 0.f;
  int stride = gridDim.x * 256;
  for (int i = blockIdx.x * 256 + t; i < n2; i += stride) {
    __half2 v = hh[i];
    float a = __half2float(v.x), b = __half2float(v.y);
    s0 += a; q0 += a * a;
    s1 += b; q1 += b * b;
  }
  atomicAdd(&ls[cb], s0);
  atomicAdd(&ls[cb + 1], s1);
  atomicAdd(&ls[64 + cb], q0);
  atomicAdd(&ls[64 + cb + 1], q1);
  __syncthreads();
  if (t < 128) atomicAdd(&stats[t], ls[t]);
}

__global__ void k_bnfinal(const float* __restrict__ stats, const float* __restrict__ gamma,
                          const float* __restrict__ beta, float* __restrict__ ss, int N) {
  int o = threadIdx.x;
  if (o < 64) {
    float fn = (float)N;
    float mean = stats[o] / fn;
    float var = stats[64 + o] / fn - mean * mean;
    float inv = rsqrtf(var + 1e-5f);
    float sc = gamma[o] * inv;
    ss[o] = sc;
    ss[64 + o] = beta[o] - mean * sc;
  }
}

__global__ void k_out2(const __half2* __restrict__ hh, const float* __restrict__ ss,
                       float2* __restrict__ out2, int n2) {
  int i = blockIdx.x * blockDim.x + threadIdx.x;
  if (i < n2) {
    int cb = (i & 31) * 2;
    __half2 v = hh[i];
    float2 o;
    o.x = __half2float(v.x) * ss[cb] + ss[64 + cb];
    o.y = __half2float(v.y) * ss[cb + 1] + ss[64 + cb + 1];
    out2[i] = o;
  }
}

// ---------------- launch ----------------

extern "C" void kernel_launch(void* const* d_in, const int* in_sizes, int n_in,
                              void* d_out, int out_size, void* d_ws, size_t ws_size,
                              hipStream_t stream) {
  const float* x     = (const float*)d_in[0];
  const int*   ei    = (const int*)d_in[1];
  const float* We    = (const float*)d_in[2];
  const float* be    = (const float*)d_in[3];
  const float* Wn    = (const float*)d_in[4];
  const float* bnode = (const float*)d_in[5];
  const float* pa    = (const float*)d_in[6];
  const float* gamma = (const float*)d_in[7];
  const float* beta  = (const float*)d_in[8];

  int N = in_sizes[0] / 64;
  int E = in_sizes[1] / 2;
  const int* srcA = ei;
  const int* dstA = ei + E;

  int NBUCK = (N + NPB - 1) / NPB;     // 391

  char* ws = (char*)d_ws;
  size_t off = 0;
  auto alloc = [&](size_t bytes) -> void* {
    void* p = (void*)(ws + off);
    off += (bytes + 255) & ~(size_t)255;
    return p;
  };
  int*    bins   = (int*)alloc((size_t)NBUCK * 4);
  int*    binoff = (int*)alloc((size_t)(NBUCK + 1) * 4);
  int*    cur    = (int*)alloc((size_t)NBUCK * 4);
  int*    packed = (int*)alloc((size_t)E * 4);
  int*    csr    = (int*)alloc((size_t)E * 4);
  int*    offA   = (int*)alloc((size_t)N * 4);
  int*    deg    = (int*)alloc((size_t)N * 4);
  __half* xh     = (__half*)alloc((size_t)N * 64 * 2);
  __half* Sh     = (__half*)alloc((size_t)N * 64 * 2);
  __half* Hh     = (__half*)alloc((size_t)N * 64 * 2);
  __half* Wfrag  = (__half*)alloc((size_t)24 * 512 * 2);
  float*  c2     = (float*)alloc(64 * 4);
  float*  stats  = (float*)alloc(128 * 4);
  float*  ssbuf  = (float*)alloc(128 * 4);

  hipMemsetAsync(bins, 0, (size_t)NBUCK * 4, stream);
  hipMemsetAsync(stats, 0, 128 * 4, stream);

  int FGRID = (E + FCHUNK - 1) / FCHUNK;   // 261
  int n4 = N * 16;
  int vgrid = (n4 + 255) / 256;
  int n2 = N * 32;
  int ntile = N / 16;                       // 6250
  int mgrid = (ntile + 3) / 4;              // 1563 blocks -> 1 tile per wave

  k_hist<<<FGRID, 256, 0, stream>>>(dstA, bins, E, FCHUNK);
  k_scan1<<<1, 1024, 0, stream>>>(bins, binoff, cur, NBUCK, E);
  k_fill3<<<FGRID, 256, 0, stream>>>(srcA, dstA, cur, packed, E);
  k_sort<<<NBUCK, 256, 0, stream>>>(packed, binoff, csr, offA, deg, N);
  k_xhalf<<<vgrid, 256, 0, stream>>>((const float4*)x, (__half2*)xh, n4);
  k_mats2<<<25, 512, 0, stream>>>(We, be, Wn, Wfrag, c2);
  k_agg<<<2048, 256, 0, stream>>>((const __half2*)xh, offA, deg, csr, (__half2*)Sh, N);
  k_nodeM<<<mgrid, 256, 0, stream>>>(xh, Sh, deg, Wfrag, c2, bnode, pa, Hh, N);
  k_stats<<<256, 256, 0, stream>>>((const __half2*)Hh, stats, n2);
  k_bnfinal<<<1, 64, 0, stream>>>(stats, gamma, beta, ssbuf, N);
  k_out2<<<(n2 + 255) / 256, 256, 0, stream>>>((const __half2*)Hh, ssbuf, (float2*)d_out, n2);
}

// Round 9
// 168.933 us; speedup vs baseline: 1.0583x; 1.0583x over previous
//
#include <hip/hip_runtime.h>
#include <hip/hip_fp16.h>

typedef _Float16 f16x8 __attribute__((ext_vector_type(8)));
typedef float f32x4 __attribute__((ext_vector_type(4)));

#define NPB 256      // nodes per bucket (dst >> 8)
#define FCHUNK 6144  // edges per fill block (24 per thread)
#define MAXBK 512    // LDS bucket array size (>= NBUCK=391)

// x fp32 -> fp16
__global__ void k_xhalf(const float4* __restrict__ x4, __half2* __restrict__ xh2, int n4) {
  int i = blockIdx.x * blockDim.x + threadIdx.x;
  if (i < n4) {
    float4 v = x4[i];
    __half2 a, b;
    a.x = __float2half_rn(v.x); a.y = __float2half_rn(v.y);
    b.x = __float2half_rn(v.z); b.y = __float2half_rn(v.w);
    xh2[2 * i] = a;
    xh2[2 * i + 1] = b;
  }
}

// global per-bucket histogram (block-local LDS first, one flush per bucket)
__global__ void k_hist(const int* __restrict__ dst, int* __restrict__ bins,
                       int E, int chunk) {
  __shared__ int lh[MAXBK];
  for (int i = threadIdx.x; i < MAXBK; i += blockDim.x) lh[i] = 0;
  __syncthreads();
  int e0 = blockIdx.x * chunk;
  int e1 = min(e0 + chunk, E);
  for (int e = e0 + threadIdx.x; e < e1; e += blockDim.x)
    atomicAdd(&lh[dst[e] >> 8], 1);
  __syncthreads();
  for (int i = threadIdx.x; i < MAXBK; i += blockDim.x)
    if (lh[i]) atomicAdd(&bins[i], lh[i]);
}

// exclusive scan of nb bins (nb <= 4096), writes binoff (+sentinel) and cursors
__global__ void k_scan1(const int* __restrict__ bins, int* __restrict__ binoff,
                        int* __restrict__ cur, int nb, int E) {
  __shared__ int lds[1024];
  int t = threadIdx.x;
  int g0 = t * 4;
  int v[4]; int s = 0;
  for (int i = 0; i < 4; ++i) { int idx = g0 + i; v[i] = (idx < nb) ? bins[idx] : 0; s += v[i]; }
  lds[t] = s;
  __syncthreads();
  for (int d = 1; d < 1024; d <<= 1) {
    int a = (t >= d) ? lds[t - d] : 0;
    __syncthreads();
    lds[t] += a;
    __syncthreads();
  }
  int ex = lds[t] - s;
  for (int i = 0; i < 4; ++i) {
    int idx = g0 + i;
    if (idx < nb) { binoff[idx] = ex; cur[idx] = ex; }
    ex += v[i];
  }
  if (t == 0) binoff[nb] = E;
}

// scatter edges into bucket segments with per-(block,bucket) reservation:
// LDS hist -> one global atomic per bucket -> direct scatter via LDS cursors.
__global__ __launch_bounds__(256) void k_fill3(const int* __restrict__ src,
    const int* __restrict__ dst, int* __restrict__ cur,
    int* __restrict__ packed, int E) {
  __shared__ int lh[MAXBK];
  __shared__ int gbase[MAXBK];
  int t = threadIdx.x;
  int e0 = blockIdx.x * FCHUNK;
  int e1 = min(e0 + FCHUNK, E);
  for (int i = t; i < MAXBK; i += 256) lh[i] = 0;
  __syncthreads();
  int dv[24];
#pragma unroll
  for (int i = 0; i < 24; ++i) {
    int e = e0 + t + i * 256;
    dv[i] = (e < e1) ? dst[e] : -1;
    if (dv[i] >= 0) atomicAdd(&lh[dv[i] >> 8], 1);
  }
  __syncthreads();
  for (int i = t; i < MAXBK; i += 256) {
    int c = lh[i];
    gbase[i] = c ? atomicAdd(&cur[i], c) : 0;
    lh[i] = 0;  // reuse as local cursor
  }
  __syncthreads();
#pragma unroll
  for (int i = 0; i < 24; ++i) {
    int d = dv[i];
    if (d >= 0) {
      int e = e0 + t + i * 256;
      int bk = d >> 8;
      int lp = atomicAdd(&lh[bk], 1);
      packed[gbase[bk] + lp] = src[e] | ((d & 255) << 20);
    }
  }
}

// per-bucket counting sort: bucket segment -> per-node CSR (+ offA, deg)
__global__ __launch_bounds__(256) void k_sort(const int* __restrict__ packed,
    const int* __restrict__ binoff, int* __restrict__ csr,
    int* __restrict__ offA, int* __restrict__ deg, int N) {
  __shared__ int hist[NPB];
  __shared__ int sc[NPB];
  __shared__ int curs[NPB];
  int b = blockIdx.x, t = threadIdx.x;
  hist[t] = 0;
  __syncthreads();
  int e0 = binoff[b], e1 = binoff[b + 1];
  for (int e = e0 + t; e < e1; e += 256)
    atomicAdd(&hist[(packed[e] >> 20) & 255], 1);
  __syncthreads();
  int v = hist[t];
  sc[t] = v;
  __syncthreads();
  for (int d = 1; d < 256; d <<= 1) {
    int a = (t >= d) ? sc[t - d] : 0;
    __syncthreads();
    sc[t] += a;
    __syncthreads();
  }
  int ex = e0 + sc[t] - v;   // global CSR start for this node
  curs[t] = ex;
  int n = b * NPB + t;
  if (n < N) { offA[n] = ex; deg[n] = v; }
  __syncthreads();
  for (int e = e0 + t; e < e1; e += 256) {
    int pk = packed[e];
    int p = atomicAdd(&curs[(pk >> 20) & 255], 1);
    csr[p] = pk & 0xFFFFF;
  }
}

// S[n] = sum over incoming edges of x[src].
// Round-7 structure (uniform scalar csr idx, full-wave 128B gathers) +
// 32-bit addressing + native fp16 accumulation (4 chains) -> ~3 VALU/edge.
__global__ void k_agg(const _Float16* __restrict__ xh, const int* __restrict__ offA,
                      const int* __restrict__ deg, const int* __restrict__ csr,
                      _Float16* __restrict__ Sh, int N) {
  unsigned lane = threadIdx.x & 63;
  int wid = (blockIdx.x * blockDim.x + threadIdx.x) >> 6;
  int nw = (gridDim.x * blockDim.x) >> 6;
  for (int n = wid; n < N; n += nw) {
    int j0 = offA[n], dg = deg[n];
    _Float16 a0 = 0, a1 = 0, a2 = 0, a3 = 0;
    int j = 0;
    for (; j + 8 <= dg; j += 8) {
      unsigned o0 = ((unsigned)csr[j0 + j + 0] << 6) | lane;
      unsigned o1 = ((unsigned)csr[j0 + j + 1] << 6) | lane;
      unsigned o2 = ((unsigned)csr[j0 + j + 2] << 6) | lane;
      unsigned o3 = ((unsigned)csr[j0 + j + 3] << 6) | lane;
      unsigned o4 = ((unsigned)csr[j0 + j + 4] << 6) | lane;
      unsigned o5 = ((unsigned)csr[j0 + j + 5] << 6) | lane;
      unsigned o6 = ((unsigned)csr[j0 + j + 6] << 6) | lane;
      unsigned o7 = ((unsigned)csr[j0 + j + 7] << 6) | lane;
      _Float16 v0 = xh[o0], v1 = xh[o1], v2 = xh[o2], v3 = xh[o3];
      _Float16 v4 = xh[o4], v5 = xh[o5], v6 = xh[o6], v7 = xh[o7];
      a0 += v0; a1 += v1; a2 += v2; a3 += v3;
      a0 += v4; a1 += v5; a2 += v6; a3 += v7;
    }
    for (; j + 4 <= dg; j += 4) {
      unsigned o0 = ((unsigned)csr[j0 + j + 0] << 6) | lane;
      unsigned o1 = ((unsigned)csr[j0 + j + 1] << 6) | lane;
      unsigned o2 = ((unsigned)csr[j0 + j + 2] << 6) | lane;
      unsigned o3 = ((unsigned)csr[j0 + j + 3] << 6) | lane;
      a0 += xh[o0]; a1 += xh[o1]; a2 += xh[o2]; a3 += xh[o3];
    }
    for (; j < dg; ++j) {
      unsigned o = ((unsigned)csr[j0 + j] << 6) | lane;
      a0 += xh[o];
    }
    Sh[((unsigned)n << 6) | lane] = (a0 + a1) + (a2 + a3);
  }
}

// build fp16 B-fragments for the 3 64x64 matrices + c2
// frag f = mat*8 + kk*4 + ct; entry t = lane*8+j holds M[kk*32+(lane>>4)*8+j][ct*16+(lane&15)]
__global__ void k_mats2(const float* __restrict__ We, const float* __restrict__ be,
                        const float* __restrict__ Wn, __half* __restrict__ Wfrag,
                        float* __restrict__ c2) {
  int b = blockIdx.x, t = threadIdx.x;
  if (b < 24) {
    int mat = b >> 3, kk = (b >> 2) & 1, ct = b & 3;
    int lane = t >> 3, j = t & 7;
    int k = kk * 32 + ((lane >> 4) & 3) * 8 + j;
    int col = ct * 16 + (lane & 15);
    float v;
    if (mat == 0) {
      v = Wn[k * 64 + col];
    } else if (mat == 1) {
      float a = 0.f;
      for (int m = 0; m < 64; ++m) a += We[k * 64 + m] * Wn[(64 + m) * 64 + col];
      v = a;
    } else {
      float a = 0.f;
      for (int m = 0; m < 64; ++m) a += We[(64 + k) * 64 + m] * Wn[(64 + m) * 64 + col];
      v = a;
    }
    Wfrag[b * 512 + t] = __float2half_rn(v);
  } else if (t < 64) {
    float a = 0.f;
    for (int m = 0; m < 64; ++m) a += be[m] * Wn[(64 + m) * 64 + t];
    c2[t] = a;
  }
}

// node model via MFMA: h = PReLU(x@M1 + S@M2 + deg*(x@M3 + c2) + b); h -> fp16
__global__ __launch_bounds__(256) void k_nodeM(const __half* __restrict__ xh,
    const __half* __restrict__ Sh, const int* __restrict__ deg,
    const __half* __restrict__ Wfrag, const float* __restrict__ c2,
    const float* __restrict__ bnode, const float* __restrict__ pa,
    __half* __restrict__ Hh, int N) {
  const f16x8* WF = (const f16x8*)Wfrag;
  int t = threadIdx.x, lane = t & 63;
  f16x8 B[24];
#pragma unroll
  for (int f = 0; f < 24; ++f) B[f] = WF[f * 64 + lane];
  float slope = pa[0];
  int wid = (blockIdx.x * blockDim.x + t) >> 6;
  int nw = (gridDim.x * blockDim.x) >> 6;
  int ntile = N >> 4;
  int r = lane & 15, g = lane >> 4;
  for (int tile = wid; tile < ntile; tile += nw) {
    int n0 = tile << 4;
    float dg[4];
#pragma unroll
    for (int q = 0; q < 4; ++q) dg[q] = (float)deg[n0 + g * 4 + q];
    const f16x8* xp = (const f16x8*)(xh + (size_t)(n0 + r) * 64 + g * 8);
    const f16x8* sp = (const f16x8*)(Sh + (size_t)(n0 + r) * 64 + g * 8);
    f16x8 ax0 = xp[0], ax1 = xp[4];
    f16x8 as0 = sp[0], as1 = sp[4];
    f32x4 accA[4], accB[4];
#pragma unroll
    for (int ct = 0; ct < 4; ++ct) {
      f32x4 a = {0.f, 0.f, 0.f, 0.f};
      a = __builtin_amdgcn_mfma_f32_16x16x32_f16(ax0, B[0 + ct], a, 0, 0, 0);
      a = __builtin_amdgcn_mfma_f32_16x16x32_f16(ax1, B[4 + ct], a, 0, 0, 0);
      a = __builtin_amdgcn_mfma_f32_16x16x32_f16(as0, B[8 + ct], a, 0, 0, 0);
      a = __builtin_amdgcn_mfma_f32_16x16x32_f16(as1, B[12 + ct], a, 0, 0, 0);
      accA[ct] = a;
      f32x4 bb = {0.f, 0.f, 0.f, 0.f};
      bb = __builtin_amdgcn_mfma_f32_16x16x32_f16(ax0, B[16 + ct], bb, 0, 0, 0);
      bb = __builtin_amdgcn_mfma_f32_16x16x32_f16(ax1, B[20 + ct], bb, 0, 0, 0);
      accB[ct] = bb;
    }
#pragma unroll
    for (int ct = 0; ct < 4; ++ct) {
      int c = ct * 16 + r;
      float cc = c2[c], bv = bnode[c];
#pragma unroll
      for (int q = 0; q < 4; ++q) {
        float hv = accA[ct][q] + dg[q] * (accB[ct][q] + cc) + bv;
        hv = hv >= 0.f ? hv : slope * hv;
        Hh[(size_t)(n0 + g * 4 + q) * 64 + c] = __float2half_rn(hv);
      }
    }
  }
}

// column sums/sumsq over Hh: reg accumulate -> LDS atomics -> 128 global atomics/block
__global__ __launch_bounds__(256) void k_stats(const __half2* __restrict__ hh,
    float* __restrict__ stats, int n2) {
  __shared__ float ls[128];
  int t = threadIdx.x;
  if (t < 128) ls[t] = 0.f;
  __syncthreads();
  int cb = (t & 31) * 2;
  float s0 = 0.f, q0 = 0.f, s1 = 0.f, q1 = 0.f;
  int stride = gridDim.x * 256;
  for (int i = blockIdx.x * 256 + t; i < n2; i += stride) {
    __half2 v = hh[i];
    float a = __half2float(v.x), b = __half2float(v.y);
    s0 += a; q0 += a * a;
    s1 += b; q1 += b * b;
  }
  atomicAdd(&ls[cb], s0);
  atomicAdd(&ls[cb + 1], s1);
  atomicAdd(&ls[64 + cb], q0);
  atomicAdd(&ls[64 + cb + 1], q1);
  __syncthreads();
  if (t < 128) atomicAdd(&stats[t], ls[t]);
}

__global__ void k_bnfinal(const float* __restrict__ stats, const float* __restrict__ gamma,
                          const float* __restrict__ beta, float* __restrict__ ss, int N) {
  int o = threadIdx.x;
  if (o < 64) {
    float fn = (float)N;
    float mean = stats[o] / fn;
    float var = stats[64 + o] / fn - mean * mean;
    float inv = rsqrtf(var + 1e-5f);
    float sc = gamma[o] * inv;
    ss[o] = sc;
    ss[64 + o] = beta[o] - mean * sc;
  }
}

__global__ void k_out2(const __half2* __restrict__ hh, const float* __restrict__ ss,
                       float2* __restrict__ out2, int n2) {
  int i = blockIdx.x * blockDim.x + threadIdx.x;
  if (i < n2) {
    int cb = (i & 31) * 2;
    __half2 v = hh[i];
    float2 o;
    o.x = __half2float(v.x) * ss[cb] + ss[64 + cb];
    o.y = __half2float(v.y) * ss[cb + 1] + ss[64 + cb + 1];
    out2[i] = o;
  }
}

// ---------------- launch ----------------

extern "C" void kernel_launch(void* const* d_in, const int* in_sizes, int n_in,
                              void* d_out, int out_size, void* d_ws, size_t ws_size,
                              hipStream_t stream) {
  const float* x     = (const float*)d_in[0];
  const int*   ei    = (const int*)d_in[1];
  const float* We    = (const float*)d_in[2];
  const float* be    = (const float*)d_in[3];
  const float* Wn    = (const float*)d_in[4];
  const float* bnode = (const float*)d_in[5];
  const float* pa    = (const float*)d_in[6];
  const float* gamma = (const float*)d_in[7];
  const float* beta  = (const float*)d_in[8];

  int N = in_sizes[0] / 64;
  int E = in_sizes[1] / 2;
  const int* srcA = ei;
  const int* dstA = ei + E;

  int NBUCK = (N + NPB - 1) / NPB;     // 391

  char* ws = (char*)d_ws;
  size_t off = 0;
  auto alloc = [&](size_t bytes) -> void* {
    void* p = (void*)(ws + off);
    off += (bytes + 255) & ~(size_t)255;
    return p;
  };
  int*    bins   = (int*)alloc((size_t)NBUCK * 4);
  int*    binoff = (int*)alloc((size_t)(NBUCK + 1) * 4);
  int*    cur    = (int*)alloc((size_t)NBUCK * 4);
  int*    packed = (int*)alloc((size_t)E * 4);
  int*    csr    = (int*)alloc((size_t)E * 4);
  int*    offA   = (int*)alloc((size_t)N * 4);
  int*    deg    = (int*)alloc((size_t)N * 4);
  __half* xh     = (__half*)alloc((size_t)N * 64 * 2);
  __half* Sh     = (__half*)alloc((size_t)N * 64 * 2);
  __half* Hh     = (__half*)alloc((size_t)N * 64 * 2);
  __half* Wfrag  = (__half*)alloc((size_t)24 * 512 * 2);
  float*  c2     = (float*)alloc(64 * 4);
  float*  stats  = (float*)alloc(128 * 4);
  float*  ssbuf  = (float*)alloc(128 * 4);

  hipMemsetAsync(bins, 0, (size_t)NBUCK * 4, stream);
  hipMemsetAsync(stats, 0, 128 * 4, stream);

  int FGRID = (E + FCHUNK - 1) / FCHUNK;   // 261
  int n4 = N * 16;
  int vgrid = (n4 + 255) / 256;
  int n2 = N * 32;
  int ntile = N / 16;                       // 6250
  int mgrid = (ntile + 3) / 4;              // 1563 blocks -> 1 tile per wave

  k_hist<<<FGRID, 256, 0, stream>>>(dstA, bins, E, FCHUNK);
  k_scan1<<<1, 1024, 0, stream>>>(bins, binoff, cur, NBUCK, E);
  k_fill3<<<FGRID, 256, 0, stream>>>(srcA, dstA, cur, packed, E);
  k_sort<<<NBUCK, 256, 0, stream>>>(packed, binoff, csr, offA, deg, N);
  k_xhalf<<<vgrid, 256, 0, stream>>>((const float4*)x, (__half2*)xh, n4);
  k_mats2<<<25, 512, 0, stream>>>(We, be, Wn, Wfrag, c2);
  k_agg<<<2048, 256, 0, stream>>>((const _Float16*)xh, offA, deg, csr, (_Float16*)Sh, N);
  k_nodeM<<<mgrid, 256, 0, stream>>>(xh, Sh, deg, Wfrag, c2, bnode, pa, Hh, N);
  k_stats<<<256, 256, 0, stream>>>((const __half2*)Hh, stats, n2);
  k_bnfinal<<<1, 64, 0, stream>>>(stats, gamma, beta, ssbuf, N);
  k_out2<<<(n2 + 255) / 256, 256, 0, stream>>>((const __half2*)Hh, ssbuf, (float2*)d_out, n2);
}

// Round 10
// 164.722 us; speedup vs baseline: 1.0853x; 1.0256x over previous
//
#include <hip/hip_runtime.h>
#include <hip/hip_fp16.h>

typedef _Float16 f16x8 __attribute__((ext_vector_type(8)));
typedef float f32x4 __attribute__((ext_vector_type(4)));

#define NPB 256      // nodes per bucket (dst >> 8)
#define FCHUNK 6144  // edges per fill block (24 per thread)
#define MAXBK 512    // LDS bucket array size (>= NBUCK=391)

// x fp32 -> fp16
__global__ void k_xhalf(const float4* __restrict__ x4, __half2* __restrict__ xh2, int n4) {
  int i = blockIdx.x * blockDim.x + threadIdx.x;
  if (i < n4) {
    float4 v = x4[i];
    __half2 a, b;
    a.x = __float2half_rn(v.x); a.y = __float2half_rn(v.y);
    b.x = __float2half_rn(v.z); b.y = __float2half_rn(v.w);
    xh2[2 * i] = a;
    xh2[2 * i + 1] = b;
  }
}

// global per-bucket histogram (block-local LDS first, one flush per bucket)
__global__ void k_hist(const int* __restrict__ dst, int* __restrict__ bins,
                       int E, int chunk) {
  __shared__ int lh[MAXBK];
  for (int i = threadIdx.x; i < MAXBK; i += blockDim.x) lh[i] = 0;
  __syncthreads();
  int e0 = blockIdx.x * chunk;
  int e1 = min(e0 + chunk, E);
  for (int e = e0 + threadIdx.x; e < e1; e += blockDim.x)
    atomicAdd(&lh[dst[e] >> 8], 1);
  __syncthreads();
  for (int i = threadIdx.x; i < MAXBK; i += blockDim.x)
    if (lh[i]) atomicAdd(&bins[i], lh[i]);
}

// exclusive scan of nb bins (nb <= 4096), writes binoff (+sentinel) and cursors
__global__ void k_scan1(const int* __restrict__ bins, int* __restrict__ binoff,
                        int* __restrict__ cur, int nb, int E) {
  __shared__ int lds[1024];
  int t = threadIdx.x;
  int g0 = t * 4;
  int v[4]; int s = 0;
  for (int i = 0; i < 4; ++i) { int idx = g0 + i; v[i] = (idx < nb) ? bins[idx] : 0; s += v[i]; }
  lds[t] = s;
  __syncthreads();
  for (int d = 1; d < 1024; d <<= 1) {
    int a = (t >= d) ? lds[t - d] : 0;
    __syncthreads();
    lds[t] += a;
    __syncthreads();
  }
  int ex = lds[t] - s;
  for (int i = 0; i < 4; ++i) {
    int idx = g0 + i;
    if (idx < nb) { binoff[idx] = ex; cur[idx] = ex; }
    ex += v[i];
  }
  if (t == 0) binoff[nb] = E;
}

// scatter edges into bucket segments with per-(block,bucket) reservation:
// LDS hist -> one global atomic per bucket -> direct scatter via LDS cursors.
__global__ __launch_bounds__(256) void k_fill3(const int* __restrict__ src,
    const int* __restrict__ dst, int* __restrict__ cur,
    int* __restrict__ packed, int E) {
  __shared__ int lh[MAXBK];
  __shared__ int gbase[MAXBK];
  int t = threadIdx.x;
  int e0 = blockIdx.x * FCHUNK;
  int e1 = min(e0 + FCHUNK, E);
  for (int i = t; i < MAXBK; i += 256) lh[i] = 0;
  __syncthreads();
  int dv[24];
#pragma unroll
  for (int i = 0; i < 24; ++i) {
    int e = e0 + t + i * 256;
    dv[i] = (e < e1) ? dst[e] : -1;
    if (dv[i] >= 0) atomicAdd(&lh[dv[i] >> 8], 1);
  }
  __syncthreads();
  for (int i = t; i < MAXBK; i += 256) {
    int c = lh[i];
    gbase[i] = c ? atomicAdd(&cur[i], c) : 0;
    lh[i] = 0;  // reuse as local cursor
  }
  __syncthreads();
#pragma unroll
  for (int i = 0; i < 24; ++i) {
    int d = dv[i];
    if (d >= 0) {
      int e = e0 + t + i * 256;
      int bk = d >> 8;
      int lp = atomicAdd(&lh[bk], 1);
      packed[gbase[bk] + lp] = src[e] | ((d & 255) << 20);
    }
  }
}

// per-bucket counting sort: bucket segment -> per-node CSR (+ offA, deg)
__global__ __launch_bounds__(256) void k_sort(const int* __restrict__ packed,
    const int* __restrict__ binoff, int* __restrict__ csr,
    int* __restrict__ offA, int* __restrict__ deg, int N) {
  __shared__ int hist[NPB];
  __shared__ int sc[NPB];
  __shared__ int curs[NPB];
  int b = blockIdx.x, t = threadIdx.x;
  hist[t] = 0;
  __syncthreads();
  int e0 = binoff[b], e1 = binoff[b + 1];
  for (int e = e0 + t; e < e1; e += 256)
    atomicAdd(&hist[(packed[e] >> 20) & 255], 1);
  __syncthreads();
  int v = hist[t];
  sc[t] = v;
  __syncthreads();
  for (int d = 1; d < 256; d <<= 1) {
    int a = (t >= d) ? sc[t - d] : 0;
    __syncthreads();
    sc[t] += a;
    __syncthreads();
  }
  int ex = e0 + sc[t] - v;   // global CSR start for this node
  curs[t] = ex;
  int n = b * NPB + t;
  if (n < N) { offA[n] = ex; deg[n] = v; }
  __syncthreads();
  for (int e = e0 + t; e < e1; e += 256) {
    int pk = packed[e];
    int p = atomicAdd(&curs[(pk >> 20) & 255], 1);
    csr[p] = pk & 0xFFFFF;
  }
}

// S[n] = sum over incoming edges of x[src].
// TWO nodes per wave interleaved (16 gathers in flight; B's loads cover A's adds).
// Wave-uniform scalar csr indices, 32-bit addressing, fp16 accumulate.
__global__ void k_agg(const _Float16* __restrict__ xh, const int* __restrict__ offA,
                      const int* __restrict__ deg, const int* __restrict__ csr,
                      _Float16* __restrict__ Sh, int N) {
  unsigned lane = threadIdx.x & 63;
  int wid = (blockIdx.x * blockDim.x + threadIdx.x) >> 6;
  int nw = (gridDim.x * blockDim.x) >> 6;
  for (int n = wid; n < N; n += 2 * nw) {
    int nB = n + nw;
    int j0A = offA[n], dgA = deg[n];
    int j0B = (nB < N) ? offA[nB] : 0;
    int dgB = (nB < N) ? deg[nB] : 0;
    _Float16 accA[4] = {0, 0, 0, 0};
    _Float16 accB[4] = {0, 0, 0, 0};
    int jA = 0, jB = 0;
    // interleaved main loop: 8 A-loads + 8 B-loads in flight together
    for (; jA + 8 <= dgA && jB + 8 <= dgB; jA += 8, jB += 8) {
      _Float16 vA[8], vB[8];
#pragma unroll
      for (int i = 0; i < 8; ++i)
        vA[i] = xh[((unsigned)csr[j0A + jA + i] << 6) | lane];
#pragma unroll
      for (int i = 0; i < 8; ++i)
        vB[i] = xh[((unsigned)csr[j0B + jB + i] << 6) | lane];
#pragma unroll
      for (int i = 0; i < 8; ++i) {
        accA[i & 3] += vA[i];
        accB[i & 3] += vB[i];
      }
    }
    // drain A 8-batches
    for (; jA + 8 <= dgA; jA += 8) {
      _Float16 vA[8];
#pragma unroll
      for (int i = 0; i < 8; ++i)
        vA[i] = xh[((unsigned)csr[j0A + jA + i] << 6) | lane];
#pragma unroll
      for (int i = 0; i < 8; ++i) accA[i & 3] += vA[i];
    }
    // drain B 8-batches
    for (; jB + 8 <= dgB; jB += 8) {
      _Float16 vB[8];
#pragma unroll
      for (int i = 0; i < 8; ++i)
        vB[i] = xh[((unsigned)csr[j0B + jB + i] << 6) | lane];
#pragma unroll
      for (int i = 0; i < 8; ++i) accB[i & 3] += vB[i];
    }
    // 4-tails
    if (jA + 4 <= dgA) {
      _Float16 vA[4];
#pragma unroll
      for (int i = 0; i < 4; ++i)
        vA[i] = xh[((unsigned)csr[j0A + jA + i] << 6) | lane];
#pragma unroll
      for (int i = 0; i < 4; ++i) accA[i] += vA[i];
      jA += 4;
    }
    if (jB + 4 <= dgB) {
      _Float16 vB[4];
#pragma unroll
      for (int i = 0; i < 4; ++i)
        vB[i] = xh[((unsigned)csr[j0B + jB + i] << 6) | lane];
#pragma unroll
      for (int i = 0; i < 4; ++i) accB[i] += vB[i];
      jB += 4;
    }
    for (; jA < dgA; ++jA)
      accA[0] += xh[((unsigned)csr[j0A + jA] << 6) | lane];
    for (; jB < dgB; ++jB)
      accB[0] += xh[((unsigned)csr[j0B + jB] << 6) | lane];
    Sh[((unsigned)n << 6) | lane] = (accA[0] + accA[1]) + (accA[2] + accA[3]);
    if (nB < N)
      Sh[((unsigned)nB << 6) | lane] = (accB[0] + accB[1]) + (accB[2] + accB[3]);
  }
}

// build fp16 B-fragments for the 3 64x64 matrices + c2
// frag f = mat*8 + kk*4 + ct; entry t = lane*8+j holds M[kk*32+(lane>>4)*8+j][ct*16+(lane&15)]
__global__ void k_mats2(const float* __restrict__ We, const float* __restrict__ be,
                        const float* __restrict__ Wn, __half* __restrict__ Wfrag,
                        float* __restrict__ c2) {
  int b = blockIdx.x, t = threadIdx.x;
  if (b < 24) {
    int mat = b >> 3, kk = (b >> 2) & 1, ct = b & 3;
    int lane = t >> 3, j = t & 7;
    int k = kk * 32 + ((lane >> 4) & 3) * 8 + j;
    int col = ct * 16 + (lane & 15);
    float v;
    if (mat == 0) {
      v = Wn[k * 64 + col];
    } else if (mat == 1) {
      float a = 0.f;
      for (int m = 0; m < 64; ++m) a += We[k * 64 + m] * Wn[(64 + m) * 64 + col];
      v = a;
    } else {
      float a = 0.f;
      for (int m = 0; m < 64; ++m) a += We[(64 + k) * 64 + m] * Wn[(64 + m) * 64 + col];
      v = a;
    }
    Wfrag[b * 512 + t] = __float2half_rn(v);
  } else if (t < 64) {
    float a = 0.f;
    for (int m = 0; m < 64; ++m) a += be[m] * Wn[(64 + m) * 64 + t];
    c2[t] = a;
  }
}

// node model via MFMA: h = PReLU(x@M1 + S@M2 + deg*(x@M3 + c2) + b); h -> fp16
__global__ __launch_bounds__(256) void k_nodeM(const __half* __restrict__ xh,
    const __half* __restrict__ Sh, const int* __restrict__ deg,
    const __half* __restrict__ Wfrag, const float* __restrict__ c2,
    const float* __restrict__ bnode, const float* __restrict__ pa,
    __half* __restrict__ Hh, int N) {
  const f16x8* WF = (const f16x8*)Wfrag;
  int t = threadIdx.x, lane = t & 63;
  f16x8 B[24];
#pragma unroll
  for (int f = 0; f < 24; ++f) B[f] = WF[f * 64 + lane];
  float slope = pa[0];
  int wid = (blockIdx.x * blockDim.x + t) >> 6;
  int nw = (gridDim.x * blockDim.x) >> 6;
  int ntile = N >> 4;
  int r = lane & 15, g = lane >> 4;
  for (int tile = wid; tile < ntile; tile += nw) {
    int n0 = tile << 4;
    float dg[4];
#pragma unroll
    for (int q = 0; q < 4; ++q) dg[q] = (float)deg[n0 + g * 4 + q];
    const f16x8* xp = (const f16x8*)(xh + (size_t)(n0 + r) * 64 + g * 8);
    const f16x8* sp = (const f16x8*)(Sh + (size_t)(n0 + r) * 64 + g * 8);
    f16x8 ax0 = xp[0], ax1 = xp[4];
    f16x8 as0 = sp[0], as1 = sp[4];
    f32x4 accA[4], accB[4];
#pragma unroll
    for (int ct = 0; ct < 4; ++ct) {
      f32x4 a = {0.f, 0.f, 0.f, 0.f};
      a = __builtin_amdgcn_mfma_f32_16x16x32_f16(ax0, B[0 + ct], a, 0, 0, 0);
      a = __builtin_amdgcn_mfma_f32_16x16x32_f16(ax1, B[4 + ct], a, 0, 0, 0);
      a = __builtin_amdgcn_mfma_f32_16x16x32_f16(as0, B[8 + ct], a, 0, 0, 0);
      a = __builtin_amdgcn_mfma_f32_16x16x32_f16(as1, B[12 + ct], a, 0, 0, 0);
      accA[ct] = a;
      f32x4 bb = {0.f, 0.f, 0.f, 0.f};
      bb = __builtin_amdgcn_mfma_f32_16x16x32_f16(ax0, B[16 + ct], bb, 0, 0, 0);
      bb = __builtin_amdgcn_mfma_f32_16x16x32_f16(ax1, B[20 + ct], bb, 0, 0, 0);
      accB[ct] = bb;
    }
#pragma unroll
    for (int ct = 0; ct < 4; ++ct) {
      int c = ct * 16 + r;
      float cc = c2[c], bv = bnode[c];
#pragma unroll
      for (int q = 0; q < 4; ++q) {
        float hv = accA[ct][q] + dg[q] * (accB[ct][q] + cc) + bv;
        hv = hv >= 0.f ? hv : slope * hv;
        Hh[(size_t)(n0 + g * 4 + q) * 64 + c] = __float2half_rn(hv);
      }
    }
  }
}

// column sums/sumsq over Hh: reg accumulate -> LDS atomics -> 128 global atomics/block
__global__ __launch_bounds__(256) void k_stats(const __half2* __restrict__ hh,
    float* __restrict__ stats, int n2) {
  __shared__ float ls[128];
  int t = threadIdx.x;
  if (t < 128) ls[t] = 0.f;
  __syncthreads();
  int cb = (t & 31) * 2;
  float s0 = 0.f, q0 = 0.f, s1 = 0.f, q1 = 0.f;
  int stride = gridDim.x * 256;
  for (int i = blockIdx.x * 256 + t; i < n2; i += stride) {
    __half2 v = hh[i];
    float a = __half2float(v.x), b = __half2float(v.y);
    s0 += a; q0 += a * a;
    s1 += b; q1 += b * b;
  }
  atomicAdd(&ls[cb], s0);
  atomicAdd(&ls[cb + 1], s1);
  atomicAdd(&ls[64 + cb], q0);
  atomicAdd(&ls[64 + cb + 1], q1);
  __syncthreads();
  if (t < 128) atomicAdd(&stats[t], ls[t]);
}

// BN finalize fused into the output pass: each thread derives scale/shift from stats
__global__ void k_out2(const __half2* __restrict__ hh, const float* __restrict__ stats,
                       const float* __restrict__ gamma, const float* __restrict__ beta,
                       float2* __restrict__ out2, int n2, float invN) {
  int i = blockIdx.x * blockDim.x + threadIdx.x;
  if (i < n2) {
    int cb = (i & 31) * 2;
    float m0 = stats[cb] * invN, m1 = stats[cb + 1] * invN;
    float v0 = stats[64 + cb] * invN - m0 * m0;
    float v1 = stats[64 + cb + 1] * invN - m1 * m1;
    float sc0 = gamma[cb] * rsqrtf(v0 + 1e-5f);
    float sc1 = gamma[cb + 1] * rsqrtf(v1 + 1e-5f);
    float sh0 = beta[cb] - m0 * sc0;
    float sh1 = beta[cb + 1] - m1 * sc1;
    __half2 v = hh[i];
    float2 o;
    o.x = __half2float(v.x) * sc0 + sh0;
    o.y = __half2float(v.y) * sc1 + sh1;
    out2[i] = o;
  }
}

// ---------------- launch ----------------

extern "C" void kernel_launch(void* const* d_in, const int* in_sizes, int n_in,
                              void* d_out, int out_size, void* d_ws, size_t ws_size,
                              hipStream_t stream) {
  const float* x     = (const float*)d_in[0];
  const int*   ei    = (const int*)d_in[1];
  const float* We    = (const float*)d_in[2];
  const float* be    = (const float*)d_in[3];
  const float* Wn    = (const float*)d_in[4];
  const float* bnode = (const float*)d_in[5];
  const float* pa    = (const float*)d_in[6];
  const float* gamma = (const float*)d_in[7];
  const float* beta  = (const float*)d_in[8];

  int N = in_sizes[0] / 64;
  int E = in_sizes[1] / 2;
  const int* srcA = ei;
  const int* dstA = ei + E;

  int NBUCK = (N + NPB - 1) / NPB;     // 391

  char* ws = (char*)d_ws;
  size_t off = 0;
  auto alloc = [&](size_t bytes) -> void* {
    void* p = (void*)(ws + off);
    off += (bytes + 255) & ~(size_t)255;
    return p;
  };
  int*    bins   = (int*)alloc((size_t)NBUCK * 4);
  int*    binoff = (int*)alloc((size_t)(NBUCK + 1) * 4);
  int*    cur    = (int*)alloc((size_t)NBUCK * 4);
  int*    packed = (int*)alloc((size_t)E * 4);
  int*    csr    = (int*)alloc((size_t)E * 4);
  int*    offA   = (int*)alloc((size_t)N * 4);
  int*    deg    = (int*)alloc((size_t)N * 4);
  __half* xh     = (__half*)alloc((size_t)N * 64 * 2);
  __half* Sh     = (__half*)alloc((size_t)N * 64 * 2);
  __half* Hh     = (__half*)alloc((size_t)N * 64 * 2);
  __half* Wfrag  = (__half*)alloc((size_t)24 * 512 * 2);
  float*  c2     = (float*)alloc(64 * 4);
  float*  stats  = (float*)alloc(128 * 4);

  hipMemsetAsync(bins, 0, (size_t)NBUCK * 4, stream);
  hipMemsetAsync(stats, 0, 128 * 4, stream);

  int FGRID = (E + FCHUNK - 1) / FCHUNK;   // 261
  int n4 = N * 16;
  int vgrid = (n4 + 255) / 256;
  int n2 = N * 32;
  int ntile = N / 16;                       // 6250
  int mgrid = (ntile + 3) / 4;              // 1563 blocks -> 1 tile per wave

  k_hist<<<FGRID, 256, 0, stream>>>(dstA, bins, E, FCHUNK);
  k_scan1<<<1, 1024, 0, stream>>>(bins, binoff, cur, NBUCK, E);
  k_fill3<<<FGRID, 256, 0, stream>>>(srcA, dstA, cur, packed, E);
  k_sort<<<NBUCK, 256, 0, stream>>>(packed, binoff, csr, offA, deg, N);
  k_xhalf<<<vgrid, 256, 0, stream>>>((const float4*)x, (__half2*)xh, n4);
  k_mats2<<<25, 512, 0, stream>>>(We, be, Wn, Wfrag, c2);
  k_agg<<<2048, 256, 0, stream>>>((const _Float16*)xh, offA, deg, csr, (_Float16*)Sh, N);
  k_nodeM<<<mgrid, 256, 0, stream>>>(xh, Sh, deg, Wfrag, c2, bnode, pa, Hh, N);
  k_stats<<<256, 256, 0, stream>>>((const __half2*)Hh, stats, n2);
  k_out2<<<(n2 + 255) / 256, 256, 0, stream>>>((const __half2*)Hh, stats, gamma, beta,
                                               (float2*)d_out, n2, 1.0f / (float)N);
}

// Round 11
// 148.680 us; speedup vs baseline: 1.2024x; 1.1079x over previous
//
#include <hip/hip_runtime.h>
#include <hip/hip_fp16.h>

typedef _Float16 f16x8 __attribute__((ext_vector_type(8)));
typedef _Float16 f16x2 __attribute__((ext_vector_type(2)));
typedef float f32x4 __attribute__((ext_vector_type(4)));

#define NPB 256      // nodes per bucket (dst >> 8)
#define FCHUNK 6144  // edges per fill/hist block (24 per thread)
#define MAXBK 512    // LDS bucket array size (>= NBUCK=391)

// fused prep: [0,FGRID) per-bucket histogram; [FGRID,FGRID+XGRID) x fp32->fp16;
// [FGRID+XGRID, +25) weight-fragment build (M1, M2=We_s@Wn_a, M3=We_d@Wn_a) + c2
__global__ __launch_bounds__(256) void k_prep(
    const float4* __restrict__ x4, __half2* __restrict__ xh2, int n4, int XGRID,
    const int* __restrict__ dst, int* __restrict__ bins, int E, int FGRID,
    const float* __restrict__ We, const float* __restrict__ be,
    const float* __restrict__ Wn, __half* __restrict__ Wfrag, float* __restrict__ c2) {
  int b = blockIdx.x, t = threadIdx.x;
  if (b < FGRID) {
    __shared__ int lh[MAXBK];
    for (int i = t; i < MAXBK; i += 256) lh[i] = 0;
    __syncthreads();
    int e0 = b * FCHUNK, e1 = min(e0 + FCHUNK, E);
    for (int e = e0 + t; e < e1; e += 256) atomicAdd(&lh[dst[e] >> 8], 1);
    __syncthreads();
    for (int i = t; i < MAXBK; i += 256)
      if (lh[i]) atomicAdd(&bins[i], lh[i]);
  } else if (b < FGRID + XGRID) {
    int i = (b - FGRID) * 256 + t;
    if (i < n4) {
      float4 v = x4[i];
      __half2 a, c;
      a.x = __float2half_rn(v.x); a.y = __float2half_rn(v.y);
      c.x = __float2half_rn(v.z); c.y = __float2half_rn(v.w);
      xh2[2 * i] = a;
      xh2[2 * i + 1] = c;
    }
  } else {
    int mb = b - FGRID - XGRID;
    if (mb < 24) {
      int mat = mb >> 3, kk = (mb >> 2) & 1, ct = mb & 3;
      for (int tt = t; tt < 512; tt += 256) {
        int lane = tt >> 3, j = tt & 7;
        int k = kk * 32 + ((lane >> 4) & 3) * 8 + j;
        int col = ct * 16 + (lane & 15);
        float v;
        if (mat == 0) {
          v = Wn[k * 64 + col];
        } else if (mat == 1) {
          float a = 0.f;
          for (int m = 0; m < 64; ++m) a += We[k * 64 + m] * Wn[(64 + m) * 64 + col];
          v = a;
        } else {
          float a = 0.f;
          for (int m = 0; m < 64; ++m) a += We[(64 + k) * 64 + m] * Wn[(64 + m) * 64 + col];
          v = a;
        }
        Wfrag[mb * 512 + tt] = __float2half_rn(v);
      }
    } else if (t < 64) {
      float a = 0.f;
      for (int m = 0; m < 64; ++m) a += be[m] * Wn[(64 + m) * 64 + t];
      c2[t] = a;
    }
  }
}

// exclusive scan of nb bins (nb <= 4096), writes binoff (+sentinel) and cursors
__global__ void k_scan1(const int* __restrict__ bins, int* __restrict__ binoff,
                        int* __restrict__ cur, int nb, int E) {
  __shared__ int lds[1024];
  int t = threadIdx.x;
  int g0 = t * 4;
  int v[4]; int s = 0;
  for (int i = 0; i < 4; ++i) { int idx = g0 + i; v[i] = (idx < nb) ? bins[idx] : 0; s += v[i]; }
  lds[t] = s;
  __syncthreads();
  for (int d = 1; d < 1024; d <<= 1) {
    int a = (t >= d) ? lds[t - d] : 0;
    __syncthreads();
    lds[t] += a;
    __syncthreads();
  }
  int ex = lds[t] - s;
  for (int i = 0; i < 4; ++i) {
    int idx = g0 + i;
    if (idx < nb) { binoff[idx] = ex; cur[idx] = ex; }
    ex += v[i];
  }
  if (t == 0) binoff[nb] = E;
}

// scatter edges into bucket segments with per-(block,bucket) reservation
__global__ __launch_bounds__(256) void k_fill3(const int* __restrict__ src,
    const int* __restrict__ dst, int* __restrict__ cur,
    int* __restrict__ packed, int E) {
  __shared__ int lh[MAXBK];
  __shared__ int gbase[MAXBK];
  int t = threadIdx.x;
  int e0 = blockIdx.x * FCHUNK;
  int e1 = min(e0 + FCHUNK, E);
  for (int i = t; i < MAXBK; i += 256) lh[i] = 0;
  __syncthreads();
  int dv[24];
#pragma unroll
  for (int i = 0; i < 24; ++i) {
    int e = e0 + t + i * 256;
    dv[i] = (e < e1) ? dst[e] : -1;
    if (dv[i] >= 0) atomicAdd(&lh[dv[i] >> 8], 1);
  }
  __syncthreads();
  for (int i = t; i < MAXBK; i += 256) {
    int c = lh[i];
    gbase[i] = c ? atomicAdd(&cur[i], c) : 0;
    lh[i] = 0;  // reuse as local cursor
  }
  __syncthreads();
#pragma unroll
  for (int i = 0; i < 24; ++i) {
    int d = dv[i];
    if (d >= 0) {
      int e = e0 + t + i * 256;
      int bk = d >> 8;
      int lp = atomicAdd(&lh[bk], 1);
      packed[gbase[bk] + lp] = src[e] | ((d & 255) << 20);
    }
  }
}

// per-bucket counting sort: bucket segment -> per-node CSR (+ offA, deg)
__global__ __launch_bounds__(256) void k_sort(const int* __restrict__ packed,
    const int* __restrict__ binoff, int* __restrict__ csr,
    int* __restrict__ offA, int* __restrict__ deg, int N) {
  __shared__ int hist[NPB];
  __shared__ int sc[NPB];
  __shared__ int curs[NPB];
  int b = blockIdx.x, t = threadIdx.x;
  hist[t] = 0;
  __syncthreads();
  int e0 = binoff[b], e1 = binoff[b + 1];
  for (int e = e0 + t; e < e1; e += 256)
    atomicAdd(&hist[(packed[e] >> 20) & 255], 1);
  __syncthreads();
  int v = hist[t];
  sc[t] = v;
  __syncthreads();
  for (int d = 1; d < 256; d <<= 1) {
    int a = (t >= d) ? sc[t - d] : 0;
    __syncthreads();
    sc[t] += a;
    __syncthreads();
  }
  int ex = e0 + sc[t] - v;   // global CSR start for this node
  curs[t] = ex;
  int n = b * NPB + t;
  if (n < N) { offA[n] = ex; deg[n] = v; }
  __syncthreads();
  for (int e = e0 + t; e < e1; e += 256) {
    int pk = packed[e];
    int p = atomicAdd(&curs[(pk >> 20) & 255], 1);
    csr[p] = pk & 0xFFFFF;
  }
}

// S[n] = sum over incoming edges of x[src].
// csr indices via readfirstlane -> scalar (SMEM) loads; gathers cover TWO rows
// per dword (lanes 0-31 = edge slot 0, lanes 32-63 = slot 1, f16x2 features);
// dual-node interleave; pk_add_f16 accumulate; shfl_xor(32) slot merge.
__global__ void k_agg(const f16x2* __restrict__ xh2, const int* __restrict__ offA,
                      const int* __restrict__ deg, const int* __restrict__ csr,
                      f16x2* __restrict__ Sh2, int N) {
  int t = threadIdx.x;
  unsigned lane = t & 63;
  unsigned f = lane & 31;          // feature-pair index
  int slot = (int)(lane >> 5);     // 0/1: which edge of a pair
  int wid = (blockIdx.x * blockDim.x + t) >> 6;
  int nw = (gridDim.x * blockDim.x) >> 6;
  for (int n = wid; n < N; n += 2 * nw) {
    int nB = n + nw;
    int j0A = offA[n], dgA = deg[n];
    int j0B = (nB < N) ? offA[nB] : 0;
    int dgB = (nB < N) ? deg[nB] : 0;
    f16x2 aA0 = {0, 0}, aA1 = {0, 0}, aB0 = {0, 0}, aB1 = {0, 0};
    int jA = 0, jB = 0;
    for (; jA + 8 <= dgA && jB + 8 <= dgB; jA += 8, jB += 8) {
      int ua = __builtin_amdgcn_readfirstlane(j0A + jA);
      int ub = __builtin_amdgcn_readfirstlane(j0B + jB);
      int a0 = csr[ua + 0], a1 = csr[ua + 1], a2 = csr[ua + 2], a3 = csr[ua + 3];
      int a4 = csr[ua + 4], a5 = csr[ua + 5], a6 = csr[ua + 6], a7 = csr[ua + 7];
      int b0 = csr[ub + 0], b1 = csr[ub + 1], b2 = csr[ub + 2], b3 = csr[ub + 3];
      int b4 = csr[ub + 4], b5 = csr[ub + 5], b6 = csr[ub + 6], b7 = csr[ub + 7];
      unsigned sA0 = (unsigned)(slot ? a1 : a0), sA1 = (unsigned)(slot ? a3 : a2);
      unsigned sA2 = (unsigned)(slot ? a5 : a4), sA3 = (unsigned)(slot ? a7 : a6);
      unsigned sB0 = (unsigned)(slot ? b1 : b0), sB1 = (unsigned)(slot ? b3 : b2);
      unsigned sB2 = (unsigned)(slot ? b5 : b4), sB3 = (unsigned)(slot ? b7 : b6);
      f16x2 vA0 = xh2[(sA0 << 5) | f], vA1 = xh2[(sA1 << 5) | f];
      f16x2 vA2 = xh2[(sA2 << 5) | f], vA3 = xh2[(sA3 << 5) | f];
      f16x2 vB0 = xh2[(sB0 << 5) | f], vB1 = xh2[(sB1 << 5) | f];
      f16x2 vB2 = xh2[(sB2 << 5) | f], vB3 = xh2[(sB3 << 5) | f];
      aA0 += vA0; aA1 += vA1; aA0 += vA2; aA1 += vA3;
      aB0 += vB0; aB1 += vB1; aB0 += vB2; aB1 += vB3;
    }
    // drain A
    for (; jA + 8 <= dgA; jA += 8) {
      int ua = __builtin_amdgcn_readfirstlane(j0A + jA);
      int a0 = csr[ua + 0], a1 = csr[ua + 1], a2 = csr[ua + 2], a3 = csr[ua + 3];
      int a4 = csr[ua + 4], a5 = csr[ua + 5], a6 = csr[ua + 6], a7 = csr[ua + 7];
      unsigned s0 = (unsigned)(slot ? a1 : a0), s1 = (unsigned)(slot ? a3 : a2);
      unsigned s2 = (unsigned)(slot ? a5 : a4), s3 = (unsigned)(slot ? a7 : a6);
      aA0 += xh2[(s0 << 5) | f]; aA1 += xh2[(s1 << 5) | f];
      aA0 += xh2[(s2 << 5) | f]; aA1 += xh2[(s3 << 5) | f];
    }
    // drain B
    for (; jB + 8 <= dgB; jB += 8) {
      int ub = __builtin_amdgcn_readfirstlane(j0B + jB);
      int b0 = csr[ub + 0], b1 = csr[ub + 1], b2 = csr[ub + 2], b3 = csr[ub + 3];
      int b4 = csr[ub + 4], b5 = csr[ub + 5], b6 = csr[ub + 6], b7 = csr[ub + 7];
      unsigned s0 = (unsigned)(slot ? b1 : b0), s1 = (unsigned)(slot ? b3 : b2);
      unsigned s2 = (unsigned)(slot ? b5 : b4), s3 = (unsigned)(slot ? b7 : b6);
      aB0 += xh2[(s0 << 5) | f]; aB1 += xh2[(s1 << 5) | f];
      aB0 += xh2[(s2 << 5) | f]; aB1 += xh2[(s3 << 5) | f];
    }
    // tails A: 4, 2, 1
    if (jA + 4 <= dgA) {
      int ua = __builtin_amdgcn_readfirstlane(j0A + jA);
      int a0 = csr[ua + 0], a1 = csr[ua + 1], a2 = csr[ua + 2], a3 = csr[ua + 3];
      unsigned s0 = (unsigned)(slot ? a1 : a0), s1 = (unsigned)(slot ? a3 : a2);
      aA0 += xh2[(s0 << 5) | f]; aA1 += xh2[(s1 << 5) | f];
      jA += 4;
    }
    if (jA + 2 <= dgA) {
      int ua = __builtin_amdgcn_readfirstlane(j0A + jA);
      int a0 = csr[ua + 0], a1 = csr[ua + 1];
      unsigned s0 = (unsigned)(slot ? a1 : a0);
      aA0 += xh2[(s0 << 5) | f];
      jA += 2;
    }
    if (jA < dgA && slot == 0) {
      unsigned s0 = (unsigned)csr[j0A + jA];
      aA1 += xh2[(s0 << 5) | f];
    }
    // tails B: 4, 2, 1
    if (jB + 4 <= dgB) {
      int ub = __builtin_amdgcn_readfirstlane(j0B + jB);
      int b0 = csr[ub + 0], b1 = csr[ub + 1], b2 = csr[ub + 2], b3 = csr[ub + 3];
      unsigned s0 = (unsigned)(slot ? b1 : b0), s1 = (unsigned)(slot ? b3 : b2);
      aB0 += xh2[(s0 << 5) | f]; aB1 += xh2[(s1 << 5) | f];
      jB += 4;
    }
    if (jB + 2 <= dgB) {
      int ub = __builtin_amdgcn_readfirstlane(j0B + jB);
      int b0 = csr[ub + 0], b1 = csr[ub + 1];
      unsigned s0 = (unsigned)(slot ? b1 : b0);
      aB0 += xh2[(s0 << 5) | f];
      jB += 2;
    }
    if (jB < dgB && slot == 0) {
      unsigned s0 = (unsigned)csr[j0B + jB];
      aB1 += xh2[(s0 << 5) | f];
    }
    // slot merge + store
    f16x2 pa = aA0 + aA1;
    unsigned ua = __builtin_bit_cast(unsigned, pa);
    unsigned ux = (unsigned)__shfl_xor((int)ua, 32);
    f16x2 totA = pa + __builtin_bit_cast(f16x2, ux);
    if (slot == 0) Sh2[((unsigned)n << 5) | f] = totA;
    if (nB < N) {
      f16x2 pb = aB0 + aB1;
      unsigned vb = __builtin_bit_cast(unsigned, pb);
      unsigned vx = (unsigned)__shfl_xor((int)vb, 32);
      f16x2 totB = pb + __builtin_bit_cast(f16x2, vx);
      if (slot == 0) Sh2[((unsigned)nB << 5) | f] = totB;
    }
  }
}

// node model via MFMA: h = PReLU(x@M1 + S@M2 + deg*(x@M3 + c2) + b); h -> fp16
__global__ __launch_bounds__(256) void k_nodeM(const __half* __restrict__ xh,
    const __half* __restrict__ Sh, const int* __restrict__ deg,
    const __half* __restrict__ Wfrag, const float* __restrict__ c2,
    const float* __restrict__ bnode, const float* __restrict__ pa,
    __half* __restrict__ Hh, int N) {
  const f16x8* WF = (const f16x8*)Wfrag;
  int t = threadIdx.x, lane = t & 63;
  f16x8 B[24];
#pragma unroll
  for (int f = 0; f < 24; ++f) B[f] = WF[f * 64 + lane];
  float slope = pa[0];
  int wid = (blockIdx.x * blockDim.x + t) >> 6;
  int nw = (gridDim.x * blockDim.x) >> 6;
  int ntile = N >> 4;
  int r = lane & 15, g = lane >> 4;
  for (int tile = wid; tile < ntile; tile += nw) {
    int n0 = tile << 4;
    float dg[4];
#pragma unroll
    for (int q = 0; q < 4; ++q) dg[q] = (float)deg[n0 + g * 4 + q];
    const f16x8* xp = (const f16x8*)(xh + (size_t)(n0 + r) * 64 + g * 8);
    const f16x8* sp = (const f16x8*)(Sh + (size_t)(n0 + r) * 64 + g * 8);
    f16x8 ax0 = xp[0], ax1 = xp[4];
    f16x8 as0 = sp[0], as1 = sp[4];
    f32x4 accA[4], accB[4];
#pragma unroll
    for (int ct = 0; ct < 4; ++ct) {
      f32x4 a = {0.f, 0.f, 0.f, 0.f};
      a = __builtin_amdgcn_mfma_f32_16x16x32_f16(ax0, B[0 + ct], a, 0, 0, 0);
      a = __builtin_amdgcn_mfma_f32_16x16x32_f16(ax1, B[4 + ct], a, 0, 0, 0);
      a = __builtin_amdgcn_mfma_f32_16x16x32_f16(as0, B[8 + ct], a, 0, 0, 0);
      a = __builtin_amdgcn_mfma_f32_16x16x32_f16(as1, B[12 + ct], a, 0, 0, 0);
      accA[ct] = a;
      f32x4 bb = {0.f, 0.f, 0.f, 0.f};
      bb = __builtin_amdgcn_mfma_f32_16x16x32_f16(ax0, B[16 + ct], bb, 0, 0, 0);
      bb = __builtin_amdgcn_mfma_f32_16x16x32_f16(ax1, B[20 + ct], bb, 0, 0, 0);
      accB[ct] = bb;
    }
#pragma unroll
    for (int ct = 0; ct < 4; ++ct) {
      int c = ct * 16 + r;
      float cc = c2[c], bv = bnode[c];
#pragma unroll
      for (int q = 0; q < 4; ++q) {
        float hv = accA[ct][q] + dg[q] * (accB[ct][q] + cc) + bv;
        hv = hv >= 0.f ? hv : slope * hv;
        Hh[(size_t)(n0 + g * 4 + q) * 64 + c] = __float2half_rn(hv);
      }
    }
  }
}

// column sums/sumsq over Hh: reg accumulate -> LDS atomics -> 128 global atomics/block
__global__ __launch_bounds__(256) void k_stats(const __half2* __restrict__ hh,
    float* __restrict__ stats, int n2) {
  __shared__ float ls[128];
  int t = threadIdx.x;
  if (t < 128) ls[t] = 0.f;
  __syncthreads();
  int cb = (t & 31) * 2;
  float s0 = 0.f, q0 = 0.f, s1 = 0.f, q1 = 0.f;
  int stride = gridDim.x * 256;
  for (int i = blockIdx.x * 256 + t; i < n2; i += stride) {
    __half2 v = hh[i];
    float a = __half2float(v.x), b = __half2float(v.y);
    s0 += a; q0 += a * a;
    s1 += b; q1 += b * b;
  }
  atomicAdd(&ls[cb], s0);
  atomicAdd(&ls[cb + 1], s1);
  atomicAdd(&ls[64 + cb], q0);
  atomicAdd(&ls[64 + cb + 1], q1);
  __syncthreads();
  if (t < 128) atomicAdd(&stats[t], ls[t]);
}

// BN finalize fused into the output pass
__global__ void k_out2(const __half2* __restrict__ hh, const float* __restrict__ stats,
                       const float* __restrict__ gamma, const float* __restrict__ beta,
                       float2* __restrict__ out2, int n2, float invN) {
  int i = blockIdx.x * blockDim.x + threadIdx.x;
  if (i < n2) {
    int cb = (i & 31) * 2;
    float m0 = stats[cb] * invN, m1 = stats[cb + 1] * invN;
    float v0 = stats[64 + cb] * invN - m0 * m0;
    float v1 = stats[64 + cb + 1] * invN - m1 * m1;
    float sc0 = gamma[cb] * rsqrtf(v0 + 1e-5f);
    float sc1 = gamma[cb + 1] * rsqrtf(v1 + 1e-5f);
    float sh0 = beta[cb] - m0 * sc0;
    float sh1 = beta[cb + 1] - m1 * sc1;
    __half2 v = hh[i];
    float2 o;
    o.x = __half2float(v.x) * sc0 + sh0;
    o.y = __half2float(v.y) * sc1 + sh1;
    out2[i] = o;
  }
}

// ---------------- launch ----------------

extern "C" void kernel_launch(void* const* d_in, const int* in_sizes, int n_in,
                              void* d_out, int out_size, void* d_ws, size_t ws_size,
                              hipStream_t stream) {
  const float* x     = (const float*)d_in[0];
  const int*   ei    = (const int*)d_in[1];
  const float* We    = (const float*)d_in[2];
  const float* be    = (const float*)d_in[3];
  const float* Wn    = (const float*)d_in[4];
  const float* bnode = (const float*)d_in[5];
  const float* pa    = (const float*)d_in[6];
  const float* gamma = (const float*)d_in[7];
  const float* beta  = (const float*)d_in[8];

  int N = in_sizes[0] / 64;
  int E = in_sizes[1] / 2;
  const int* srcA = ei;
  const int* dstA = ei + E;

  int NBUCK = (N + NPB - 1) / NPB;     // 391

  char* ws = (char*)d_ws;
  size_t off = 0;
  auto alloc = [&](size_t bytes) -> void* {
    void* p = (void*)(ws + off);
    off += (bytes + 255) & ~(size_t)255;
    return p;
  };
  // bins and stats share one zeroed block (single memset)
  int*    bins   = (int*)alloc((size_t)(NBUCK + 128) * 4);
  float*  stats  = (float*)(bins + NBUCK);
  int*    binoff = (int*)alloc((size_t)(NBUCK + 1) * 4);
  int*    cur    = (int*)alloc((size_t)NBUCK * 4);
  int*    packed = (int*)alloc((size_t)E * 4);
  int*    csr    = (int*)alloc((size_t)E * 4);
  int*    offA   = (int*)alloc((size_t)N * 4);
  int*    deg    = (int*)alloc((size_t)N * 4);
  __half* xh     = (__half*)alloc((size_t)N * 64 * 2);
  __half* Sh     = (__half*)alloc((size_t)N * 64 * 2);
  __half* Hh     = (__half*)alloc((size_t)N * 64 * 2);
  __half* Wfrag  = (__half*)alloc((size_t)24 * 512 * 2);
  float*  c2     = (float*)alloc(64 * 4);

  hipMemsetAsync(bins, 0, (size_t)(NBUCK + 128) * 4, stream);

  int FGRID = (E + FCHUNK - 1) / FCHUNK;   // 261
  int n4 = N * 16;
  int XGRID = (n4 + 255) / 256;            // 6250
  int n2 = N * 32;
  int ntile = N / 16;                       // 6250
  int mgrid = (ntile + 3) / 4;              // 1563 blocks -> 1 tile per wave

  k_prep<<<FGRID + XGRID + 25, 256, 0, stream>>>(
      (const float4*)x, (__half2*)xh, n4, XGRID,
      dstA, bins, E, FGRID, We, be, Wn, Wfrag, c2);
  k_scan1<<<1, 1024, 0, stream>>>(bins, binoff, cur, NBUCK, E);
  k_fill3<<<FGRID, 256, 0, stream>>>(srcA, dstA, cur, packed, E);
  k_sort<<<NBUCK, 256, 0, stream>>>(packed, binoff, csr, offA, deg, N);
  k_agg<<<2048, 256, 0, stream>>>((const f16x2*)xh, offA, deg, csr, (f16x2*)Sh, N);
  k_nodeM<<<mgrid, 256, 0, stream>>>(xh, Sh, deg, Wfrag, c2, bnode, pa, Hh, N);
  k_stats<<<256, 256, 0, stream>>>((const __half2*)Hh, stats, n2);
  k_out2<<<(n2 + 255) / 256, 256, 0, stream>>>((const __half2*)Hh, stats, gamma, beta,
                                               (float2*)d_out, n2, 1.0f / (float)N);
}

// Round 12
// 146.363 us; speedup vs baseline: 1.2215x; 1.0158x over previous
//
#include <hip/hip_runtime.h>
#include <hip/hip_fp16.h>

typedef _Float16 f16x8 __attribute__((ext_vector_type(8)));
typedef _Float16 f16x2 __attribute__((ext_vector_type(2)));
typedef float f32x4 __attribute__((ext_vector_type(4)));

#define NPB 256      // nodes per bucket (dst >> 8)
#define FCHUNK 6144  // edges per fill/hist block (24 per thread)
#define MAXBK 512    // LDS bucket array size (>= NBUCK=391)

// zero bins+stats (replaces hipMemsetAsync -> fillBufferAligned, which cost ~40us/replay)
__global__ void k_zero(int* __restrict__ p, int n) {
  for (int i = threadIdx.x; i < n; i += 256) p[i] = 0;
}

// fused prep: [0,FGRID) per-bucket histogram; [FGRID,FGRID+XGRID) x fp32->fp16;
// [FGRID+XGRID, +25) weight-fragment build (M1, M2=We_s@Wn_a, M3=We_d@Wn_a) + c2
__global__ __launch_bounds__(256) void k_prep(
    const float4* __restrict__ x4, __half2* __restrict__ xh2, int n4, int XGRID,
    const int* __restrict__ dst, int* __restrict__ bins, int E, int FGRID,
    const float* __restrict__ We, const float* __restrict__ be,
    const float* __restrict__ Wn, __half* __restrict__ Wfrag, float* __restrict__ c2) {
  int b = blockIdx.x, t = threadIdx.x;
  if (b < FGRID) {
    __shared__ int lh[MAXBK];
    for (int i = t; i < MAXBK; i += 256) lh[i] = 0;
    __syncthreads();
    int e0 = b * FCHUNK, e1 = min(e0 + FCHUNK, E);
    for (int e = e0 + t; e < e1; e += 256) atomicAdd(&lh[dst[e] >> 8], 1);
    __syncthreads();
    for (int i = t; i < MAXBK; i += 256)
      if (lh[i]) atomicAdd(&bins[i], lh[i]);
  } else if (b < FGRID + XGRID) {
    int i = (b - FGRID) * 256 + t;
    if (i < n4) {
      float4 v = x4[i];
      __half2 a, c;
      a.x = __float2half_rn(v.x); a.y = __float2half_rn(v.y);
      c.x = __float2half_rn(v.z); c.y = __float2half_rn(v.w);
      xh2[2 * i] = a;
      xh2[2 * i + 1] = c;
    }
  } else {
    int mb = b - FGRID - XGRID;
    if (mb < 24) {
      int mat = mb >> 3, kk = (mb >> 2) & 1, ct = mb & 3;
      for (int tt = t; tt < 512; tt += 256) {
        int lane = tt >> 3, j = tt & 7;
        int k = kk * 32 + ((lane >> 4) & 3) * 8 + j;
        int col = ct * 16 + (lane & 15);
        float v;
        if (mat == 0) {
          v = Wn[k * 64 + col];
        } else if (mat == 1) {
          float a = 0.f;
          for (int m = 0; m < 64; ++m) a += We[k * 64 + m] * Wn[(64 + m) * 64 + col];
          v = a;
        } else {
          float a = 0.f;
          for (int m = 0; m < 64; ++m) a += We[(64 + k) * 64 + m] * Wn[(64 + m) * 64 + col];
          v = a;
        }
        Wfrag[mb * 512 + tt] = __float2half_rn(v);
      }
    } else if (t < 64) {
      float a = 0.f;
      for (int m = 0; m < 64; ++m) a += be[m] * Wn[(64 + m) * 64 + t];
      c2[t] = a;
    }
  }
}

// exclusive scan of nb bins (nb <= 4096), writes binoff (+sentinel) and cursors
__global__ void k_scan1(const int* __restrict__ bins, int* __restrict__ binoff,
                        int* __restrict__ cur, int nb, int E) {
  __shared__ int lds[1024];
  int t = threadIdx.x;
  int g0 = t * 4;
  int v[4]; int s = 0;
  for (int i = 0; i < 4; ++i) { int idx = g0 + i; v[i] = (idx < nb) ? bins[idx] : 0; s += v[i]; }
  lds[t] = s;
  __syncthreads();
  for (int d = 1; d < 1024; d <<= 1) {
    int a = (t >= d) ? lds[t - d] : 0;
    __syncthreads();
    lds[t] += a;
    __syncthreads();
  }
  int ex = lds[t] - s;
  for (int i = 0; i < 4; ++i) {
    int idx = g0 + i;
    if (idx < nb) { binoff[idx] = ex; cur[idx] = ex; }
    ex += v[i];
  }
  if (t == 0) binoff[nb] = E;
}

// scatter edges into bucket segments with per-(block,bucket) reservation
__global__ __launch_bounds__(256) void k_fill3(const int* __restrict__ src,
    const int* __restrict__ dst, int* __restrict__ cur,
    int* __restrict__ packed, int E) {
  __shared__ int lh[MAXBK];
  __shared__ int gbase[MAXBK];
  int t = threadIdx.x;
  int e0 = blockIdx.x * FCHUNK;
  int e1 = min(e0 + FCHUNK, E);
  for (int i = t; i < MAXBK; i += 256) lh[i] = 0;
  __syncthreads();
  int dv[24];
#pragma unroll
  for (int i = 0; i < 24; ++i) {
    int e = e0 + t + i * 256;
    dv[i] = (e < e1) ? dst[e] : -1;
    if (dv[i] >= 0) atomicAdd(&lh[dv[i] >> 8], 1);
  }
  __syncthreads();
  for (int i = t; i < MAXBK; i += 256) {
    int c = lh[i];
    gbase[i] = c ? atomicAdd(&cur[i], c) : 0;
    lh[i] = 0;  // reuse as local cursor
  }
  __syncthreads();
#pragma unroll
  for (int i = 0; i < 24; ++i) {
    int d = dv[i];
    if (d >= 0) {
      int e = e0 + t + i * 256;
      int bk = d >> 8;
      int lp = atomicAdd(&lh[bk], 1);
      packed[gbase[bk] + lp] = src[e] | ((d & 255) << 20);
    }
  }
}

// per-bucket counting sort: bucket segment -> per-node CSR (+ offA, deg)
__global__ __launch_bounds__(256) void k_sort(const int* __restrict__ packed,
    const int* __restrict__ binoff, int* __restrict__ csr,
    int* __restrict__ offA, int* __restrict__ deg, int N) {
  __shared__ int hist[NPB];
  __shared__ int sc[NPB];
  __shared__ int curs[NPB];
  int b = blockIdx.x, t = threadIdx.x;
  hist[t] = 0;
  __syncthreads();
  int e0 = binoff[b], e1 = binoff[b + 1];
  for (int e = e0 + t; e < e1; e += 256)
    atomicAdd(&hist[(packed[e] >> 20) & 255], 1);
  __syncthreads();
  int v = hist[t];
  sc[t] = v;
  __syncthreads();
  for (int d = 1; d < 256; d <<= 1) {
    int a = (t >= d) ? sc[t - d] : 0;
    __syncthreads();
    sc[t] += a;
    __syncthreads();
  }
  int ex = e0 + sc[t] - v;   // global CSR start for this node
  curs[t] = ex;
  int n = b * NPB + t;
  if (n < N) { offA[n] = ex; deg[n] = v; }
  __syncthreads();
  for (int e = e0 + t; e < e1; e += 256) {
    int pk = packed[e];
    int p = atomicAdd(&curs[(pk >> 20) & 255], 1);
    csr[p] = pk & 0xFFFFF;
  }
}

// S[n] = sum over incoming edges of x[src].
// csr indices via readfirstlane -> scalar (SMEM) loads; gathers cover TWO rows
// per dword (lanes 0-31 = edge slot 0, lanes 32-63 = slot 1, f16x2 features);
// dual-node interleave; pk_add_f16 accumulate; shfl_xor(32) slot merge.
__global__ void k_agg(const f16x2* __restrict__ xh2, const int* __restrict__ offA,
                      const int* __restrict__ deg, const int* __restrict__ csr,
                      f16x2* __restrict__ Sh2, int N) {
  int t = threadIdx.x;
  unsigned lane = t & 63;
  unsigned f = lane & 31;          // feature-pair index
  int slot = (int)(lane >> 5);     // 0/1: which edge of a pair
  int wid = (blockIdx.x * blockDim.x + t) >> 6;
  int nw = (gridDim.x * blockDim.x) >> 6;
  for (int n = wid; n < N; n += 2 * nw) {
    int nB = n + nw;
    int j0A = offA[n], dgA = deg[n];
    int j0B = (nB < N) ? offA[nB] : 0;
    int dgB = (nB < N) ? deg[nB] : 0;
    f16x2 aA0 = {0, 0}, aA1 = {0, 0}, aB0 = {0, 0}, aB1 = {0, 0};
    int jA = 0, jB = 0;
    for (; jA + 8 <= dgA && jB + 8 <= dgB; jA += 8, jB += 8) {
      int ua = __builtin_amdgcn_readfirstlane(j0A + jA);
      int ub = __builtin_amdgcn_readfirstlane(j0B + jB);
      int a0 = csr[ua + 0], a1 = csr[ua + 1], a2 = csr[ua + 2], a3 = csr[ua + 3];
      int a4 = csr[ua + 4], a5 = csr[ua + 5], a6 = csr[ua + 6], a7 = csr[ua + 7];
      int b0 = csr[ub + 0], b1 = csr[ub + 1], b2 = csr[ub + 2], b3 = csr[ub + 3];
      int b4 = csr[ub + 4], b5 = csr[ub + 5], b6 = csr[ub + 6], b7 = csr[ub + 7];
      unsigned sA0 = (unsigned)(slot ? a1 : a0), sA1 = (unsigned)(slot ? a3 : a2);
      unsigned sA2 = (unsigned)(slot ? a5 : a4), sA3 = (unsigned)(slot ? a7 : a6);
      unsigned sB0 = (unsigned)(slot ? b1 : b0), sB1 = (unsigned)(slot ? b3 : b2);
      unsigned sB2 = (unsigned)(slot ? b5 : b4), sB3 = (unsigned)(slot ? b7 : b6);
      f16x2 vA0 = xh2[(sA0 << 5) | f], vA1 = xh2[(sA1 << 5) | f];
      f16x2 vA2 = xh2[(sA2 << 5) | f], vA3 = xh2[(sA3 << 5) | f];
      f16x2 vB0 = xh2[(sB0 << 5) | f], vB1 = xh2[(sB1 << 5) | f];
      f16x2 vB2 = xh2[(sB2 << 5) | f], vB3 = xh2[(sB3 << 5) | f];
      aA0 += vA0; aA1 += vA1; aA0 += vA2; aA1 += vA3;
      aB0 += vB0; aB1 += vB1; aB0 += vB2; aB1 += vB3;
    }
    // drain A
    for (; jA + 8 <= dgA; jA += 8) {
      int ua = __builtin_amdgcn_readfirstlane(j0A + jA);
      int a0 = csr[ua + 0], a1 = csr[ua + 1], a2 = csr[ua + 2], a3 = csr[ua + 3];
      int a4 = csr[ua + 4], a5 = csr[ua + 5], a6 = csr[ua + 6], a7 = csr[ua + 7];
      unsigned s0 = (unsigned)(slot ? a1 : a0), s1 = (unsigned)(slot ? a3 : a2);
      unsigned s2 = (unsigned)(slot ? a5 : a4), s3 = (unsigned)(slot ? a7 : a6);
      aA0 += xh2[(s0 << 5) | f]; aA1 += xh2[(s1 << 5) | f];
      aA0 += xh2[(s2 << 5) | f]; aA1 += xh2[(s3 << 5) | f];
    }
    // drain B
    for (; jB + 8 <= dgB; jB += 8) {
      int ub = __builtin_amdgcn_readfirstlane(j0B + jB);
      int b0 = csr[ub + 0], b1 = csr[ub + 1], b2 = csr[ub + 2], b3 = csr[ub + 3];
      int b4 = csr[ub + 4], b5 = csr[ub + 5], b6 = csr[ub + 6], b7 = csr[ub + 7];
      unsigned s0 = (unsigned)(slot ? b1 : b0), s1 = (unsigned)(slot ? b3 : b2);
      unsigned s2 = (unsigned)(slot ? b5 : b4), s3 = (unsigned)(slot ? b7 : b6);
      aB0 += xh2[(s0 << 5) | f]; aB1 += xh2[(s1 << 5) | f];
      aB0 += xh2[(s2 << 5) | f]; aB1 += xh2[(s3 << 5) | f];
    }
    // tails A: 4, 2, 1
    if (jA + 4 <= dgA) {
      int ua = __builtin_amdgcn_readfirstlane(j0A + jA);
      int a0 = csr[ua + 0], a1 = csr[ua + 1], a2 = csr[ua + 2], a3 = csr[ua + 3];
      unsigned s0 = (unsigned)(slot ? a1 : a0), s1 = (unsigned)(slot ? a3 : a2);
      aA0 += xh2[(s0 << 5) | f]; aA1 += xh2[(s1 << 5) | f];
      jA += 4;
    }
    if (jA + 2 <= dgA) {
      int ua = __builtin_amdgcn_readfirstlane(j0A + jA);
      int a0 = csr[ua + 0], a1 = csr[ua + 1];
      unsigned s0 = (unsigned)(slot ? a1 : a0);
      aA0 += xh2[(s0 << 5) | f];
      jA += 2;
    }
    if (jA < dgA && slot == 0) {
      unsigned s0 = (unsigned)csr[j0A + jA];
      aA1 += xh2[(s0 << 5) | f];
    }
    // tails B: 4, 2, 1
    if (jB + 4 <= dgB) {
      int ub = __builtin_amdgcn_readfirstlane(j0B + jB);
      int b0 = csr[ub + 0], b1 = csr[ub + 1], b2 = csr[ub + 2], b3 = csr[ub + 3];
      unsigned s0 = (unsigned)(slot ? b1 : b0), s1 = (unsigned)(slot ? b3 : b2);
      aB0 += xh2[(s0 << 5) | f]; aB1 += xh2[(s1 << 5) | f];
      jB += 4;
    }
    if (jB + 2 <= dgB) {
      int ub = __builtin_amdgcn_readfirstlane(j0B + jB);
      int b0 = csr[ub + 0], b1 = csr[ub + 1];
      unsigned s0 = (unsigned)(slot ? b1 : b0);
      aB0 += xh2[(s0 << 5) | f];
      jB += 2;
    }
    if (jB < dgB && slot == 0) {
      unsigned s0 = (unsigned)csr[j0B + jB];
      aB1 += xh2[(s0 << 5) | f];
    }
    // slot merge + store
    f16x2 pa = aA0 + aA1;
    unsigned ua = __builtin_bit_cast(unsigned, pa);
    unsigned ux = (unsigned)__shfl_xor((int)ua, 32);
    f16x2 totA = pa + __builtin_bit_cast(f16x2, ux);
    if (slot == 0) Sh2[((unsigned)n << 5) | f] = totA;
    if (nB < N) {
      f16x2 pb = aB0 + aB1;
      unsigned vb = __builtin_bit_cast(unsigned, pb);
      unsigned vx = (unsigned)__shfl_xor((int)vb, 32);
      f16x2 totB = pb + __builtin_bit_cast(f16x2, vx);
      if (slot == 0) Sh2[((unsigned)nB << 5) | f] = totB;
    }
  }
}

// node model via MFMA: h = PReLU(x@M1 + S@M2 + deg*(x@M3 + c2) + b); h -> fp16
__global__ __launch_bounds__(256) void k_nodeM(const __half* __restrict__ xh,
    const __half* __restrict__ Sh, const int* __restrict__ deg,
    const __half* __restrict__ Wfrag, const float* __restrict__ c2,
    const float* __restrict__ bnode, const float* __restrict__ pa,
    __half* __restrict__ Hh, int N) {
  const f16x8* WF = (const f16x8*)Wfrag;
  int t = threadIdx.x, lane = t & 63;
  f16x8 B[24];
#pragma unroll
  for (int f = 0; f < 24; ++f) B[f] = WF[f * 64 + lane];
  float slope = pa[0];
  int wid = (blockIdx.x * blockDim.x + t) >> 6;
  int nw = (gridDim.x * blockDim.x) >> 6;
  int ntile = N >> 4;
  int r = lane & 15, g = lane >> 4;
  for (int tile = wid; tile < ntile; tile += nw) {
    int n0 = tile << 4;
    float dg[4];
#pragma unroll
    for (int q = 0; q < 4; ++q) dg[q] = (float)deg[n0 + g * 4 + q];
    const f16x8* xp = (const f16x8*)(xh + (size_t)(n0 + r) * 64 + g * 8);
    const f16x8* sp = (const f16x8*)(Sh + (size_t)(n0 + r) * 64 + g * 8);
    f16x8 ax0 = xp[0], ax1 = xp[4];
    f16x8 as0 = sp[0], as1 = sp[4];
    f32x4 accA[4], accB[4];
#pragma unroll
    for (int ct = 0; ct < 4; ++ct) {
      f32x4 a = {0.f, 0.f, 0.f, 0.f};
      a = __builtin_amdgcn_mfma_f32_16x16x32_f16(ax0, B[0 + ct], a, 0, 0, 0);
      a = __builtin_amdgcn_mfma_f32_16x16x32_f16(ax1, B[4 + ct], a, 0, 0, 0);
      a = __builtin_amdgcn_mfma_f32_16x16x32_f16(as0, B[8 + ct], a, 0, 0, 0);
      a = __builtin_amdgcn_mfma_f32_16x16x32_f16(as1, B[12 + ct], a, 0, 0, 0);
      accA[ct] = a;
      f32x4 bb = {0.f, 0.f, 0.f, 0.f};
      bb = __builtin_amdgcn_mfma_f32_16x16x32_f16(ax0, B[16 + ct], bb, 0, 0, 0);
      bb = __builtin_amdgcn_mfma_f32_16x16x32_f16(ax1, B[20 + ct], bb, 0, 0, 0);
      accB[ct] = bb;
    }
#pragma unroll
    for (int ct = 0; ct < 4; ++ct) {
      int c = ct * 16 + r;
      float cc = c2[c], bv = bnode[c];
#pragma unroll
      for (int q = 0; q < 4; ++q) {
        float hv = accA[ct][q] + dg[q] * (accB[ct][q] + cc) + bv;
        hv = hv >= 0.f ? hv : slope * hv;
        Hh[(size_t)(n0 + g * 4 + q) * 64 + c] = __float2half_rn(hv);
      }
    }
  }
}

// column sums/sumsq over Hh: reg accumulate -> LDS atomics -> 128 global atomics/block
__global__ __launch_bounds__(256) void k_stats(const __half2* __restrict__ hh,
    float* __restrict__ stats, int n2) {
  __shared__ float ls[128];
  int t = threadIdx.x;
  if (t < 128) ls[t] = 0.f;
  __syncthreads();
  int cb = (t & 31) * 2;
  float s0 = 0.f, q0 = 0.f, s1 = 0.f, q1 = 0.f;
  int stride = gridDim.x * 256;
  for (int i = blockIdx.x * 256 + t; i < n2; i += stride) {
    __half2 v = hh[i];
    float a = __half2float(v.x), b = __half2float(v.y);
    s0 += a; q0 += a * a;
    s1 += b; q1 += b * b;
  }
  atomicAdd(&ls[cb], s0);
  atomicAdd(&ls[cb + 1], s1);
  atomicAdd(&ls[64 + cb], q0);
  atomicAdd(&ls[64 + cb + 1], q1);
  __syncthreads();
  if (t < 128) atomicAdd(&stats[t], ls[t]);
}

// BN finalize fused into the output pass
__global__ void k_out2(const __half2* __restrict__ hh, const float* __restrict__ stats,
                       const float* __restrict__ gamma, const float* __restrict__ beta,
                       float2* __restrict__ out2, int n2, float invN) {
  int i = blockIdx.x * blockDim.x + threadIdx.x;
  if (i < n2) {
    int cb = (i & 31) * 2;
    float m0 = stats[cb] * invN, m1 = stats[cb + 1] * invN;
    float v0 = stats[64 + cb] * invN - m0 * m0;
    float v1 = stats[64 + cb + 1] * invN - m1 * m1;
    float sc0 = gamma[cb] * rsqrtf(v0 + 1e-5f);
    float sc1 = gamma[cb + 1] * rsqrtf(v1 + 1e-5f);
    float sh0 = beta[cb] - m0 * sc0;
    float sh1 = beta[cb + 1] - m1 * sc1;
    __half2 v = hh[i];
    float2 o;
    o.x = __half2float(v.x) * sc0 + sh0;
    o.y = __half2float(v.y) * sc1 + sh1;
    out2[i] = o;
  }
}

// ---------------- launch ----------------

extern "C" void kernel_launch(void* const* d_in, const int* in_sizes, int n_in,
                              void* d_out, int out_size, void* d_ws, size_t ws_size,
                              hipStream_t stream) {
  const float* x     = (const float*)d_in[0];
  const int*   ei    = (const int*)d_in[1];
  const float* We    = (const float*)d_in[2];
  const float* be    = (const float*)d_in[3];
  const float* Wn    = (const float*)d_in[4];
  const float* bnode = (const float*)d_in[5];
  const float* pa    = (const float*)d_in[6];
  const float* gamma = (const float*)d_in[7];
  const float* beta  = (const float*)d_in[8];

  int N = in_sizes[0] / 64;
  int E = in_sizes[1] / 2;
  const int* srcA = ei;
  const int* dstA = ei + E;

  int NBUCK = (N + NPB - 1) / NPB;     // 391

  char* ws = (char*)d_ws;
  size_t off = 0;
  auto alloc = [&](size_t bytes) -> void* {
    void* p = (void*)(ws + off);
    off += (bytes + 255) & ~(size_t)255;
    return p;
  };
  // bins and stats share one zeroed block (single k_zero)
  int*    bins   = (int*)alloc((size_t)(NBUCK + 128) * 4);
  float*  stats  = (float*)(bins + NBUCK);
  int*    binoff = (int*)alloc((size_t)(NBUCK + 1) * 4);
  int*    cur    = (int*)alloc((size_t)NBUCK * 4);
  int*    packed = (int*)alloc((size_t)E * 4);
  int*    csr    = (int*)alloc((size_t)E * 4);
  int*    offA   = (int*)alloc((size_t)N * 4);
  int*    deg    = (int*)alloc((size_t)N * 4);
  __half* xh     = (__half*)alloc((size_t)N * 64 * 2);
  __half* Sh     = (__half*)alloc((size_t)N * 64 * 2);
  __half* Hh     = (__half*)alloc((size_t)N * 64 * 2);
  __half* Wfrag  = (__half*)alloc((size_t)24 * 512 * 2);
  float*  c2     = (float*)alloc(64 * 4);

  int FGRID = (E + FCHUNK - 1) / FCHUNK;   // 261
  int n4 = N * 16;
  int XGRID = (n4 + 255) / 256;            // 6250
  int n2 = N * 32;
  int ntile = N / 16;                       // 6250
  int mgrid = (ntile + 3) / 4;              // 1563 blocks -> 1 tile per wave

  k_zero<<<1, 256, 0, stream>>>(bins, NBUCK + 128);
  k_prep<<<FGRID + XGRID + 25, 256, 0, stream>>>(
      (const float4*)x, (__half2*)xh, n4, XGRID,
      dstA, bins, E, FGRID, We, be, Wn, Wfrag, c2);
  k_scan1<<<1, 1024, 0, stream>>>(bins, binoff, cur, NBUCK, E);
  k_fill3<<<FGRID, 256, 0, stream>>>(srcA, dstA, cur, packed, E);
  k_sort<<<NBUCK, 256, 0, stream>>>(packed, binoff, csr, offA, deg, N);
  k_agg<<<2048, 256, 0, stream>>>((const f16x2*)xh, offA, deg, csr, (f16x2*)Sh, N);
  k_nodeM<<<mgrid, 256, 0, stream>>>(xh, Sh, deg, Wfrag, c2, bnode, pa, Hh, N);
  k_stats<<<256, 256, 0, stream>>>((const __half2*)Hh, stats, n2);
  k_out2<<<(n2 + 255) / 256, 256, 0, stream>>>((const __half2*)Hh, stats, gamma, beta,
                                               (float2*)d_out, n2, 1.0f / (float)N);
}